// Round 7
// baseline (224.180 us; speedup 1.0000x reference)
//
#include <hip/hip_runtime.h>
#include <hip/hip_bf16.h>
#include <math.h>

typedef short bf16x8 __attribute__((ext_vector_type(8)));
typedef float f32x4 __attribute__((ext_vector_type(4)));

#define LROW 72   // padded LDS row for P (bf16 elems): 2-way alias, free
#define NSPLIT 6  // flash split-K chunks

__device__ __forceinline__ unsigned short f2bf(float f) {
  union { float f; unsigned int u; } v; v.f = f;
  unsigned int u = v.u;
  unsigned int r = (u + 0x7fffu + ((u >> 16) & 1u)) >> 16;
  return (unsigned short)r;
}
__device__ __forceinline__ float bf2f(unsigned short u) {
  return __uint_as_float((unsigned)u << 16);
}

#if __has_builtin(__builtin_amdgcn_global_load_lds)
#define HAVE_GLD 1
__device__ __forceinline__ void gld16(const void* g, void* l) {
  __builtin_amdgcn_global_load_lds(
      (const __attribute__((address_space(1))) unsigned int*)g,
      (__attribute__((address_space(3))) unsigned int*)l, 16, 0, 0);
}
#else
#define HAVE_GLD 0
#endif

// All fp32->bf16 converts: x (4096 blk), Wq(1024), Wk(256), Wv(256), Wproj(1024)
__global__ __launch_bounds__(256) void cvt_all_kernel(const float* __restrict__ x,
                                                      const float* __restrict__ Wq,
                                                      const float* __restrict__ Wk,
                                                      const float* __restrict__ Wv,
                                                      const float* __restrict__ Wproj,
                                                      unsigned short* __restrict__ xb,
                                                      unsigned short* __restrict__ wqkv,
                                                      unsigned short* __restrict__ wpj) {
  int blk = blockIdx.x;
  const float* src;
  unsigned short* dst;
  if (blk < 4096)      { src = x + (size_t)blk * 1024;            dst = xb + (size_t)blk * 1024; }
  else if (blk < 5120) { src = Wq + (size_t)(blk - 4096) * 1024;  dst = wqkv + (size_t)(blk - 4096) * 1024; }
  else if (blk < 5376) { src = Wk + (size_t)(blk - 5120) * 1024;  dst = wqkv + (size_t)(blk - 4096) * 1024; }
  else if (blk < 5632) { src = Wv + (size_t)(blk - 5376) * 1024;  dst = wqkv + (size_t)(blk - 4096) * 1024; }
  else                 { src = Wproj + (size_t)(blk - 5632) * 1024; dst = wpj + (size_t)(blk - 5632) * 1024; }
  int i = threadIdx.x;
  float4 v = ((const float4*)src)[i];
  ushort4 o;
  o.x = f2bf(v.x); o.y = f2bf(v.y); o.z = f2bf(v.z); o.w = f2bf(v.w);
  ((ushort4*)dst)[i] = o;
}

// Plain GEMM C[M][N] = A[M][K] x B[N][K]^T; 128x128 tile, BK=64, gld16 staging, XOR swizzle.
__global__ __launch_bounds__(256) void gemm128_kernel(const unsigned short* __restrict__ A,
                                                      const unsigned short* __restrict__ B,
                                                      float* __restrict__ C, int M, int N, int K) {
  __shared__ unsigned short As[128 * 64];
  __shared__ unsigned short Bs[128 * 64];
  int tid = threadIdx.x;
  int wave = tid >> 6, lane = tid & 63, l15 = lane & 15, quad = lane >> 4;
  int wm = (wave >> 1) * 64, wn = (wave & 1) * 64;
  int n0 = blockIdx.x * 128, m0 = blockIdx.y * 128;
  f32x4 acc[4][4];
#pragma unroll
  for (int i = 0; i < 4; i++)
#pragma unroll
    for (int j = 0; j < 4; j++) acc[i][j] = (f32x4){0.f, 0.f, 0.f, 0.f};
  int srow = lane >> 3;
  int scol = ((lane & 7) ^ srow) * 8;
  for (int k0 = 0; k0 < K; k0 += 64) {
    __syncthreads();
#if HAVE_GLD
#pragma unroll
    for (int i = 0; i < 4; i++) {
      int row = wave * 32 + i * 8;
      gld16(A + (size_t)(m0 + row + srow) * K + k0 + scol, As + row * 64 + lane * 8);
      gld16(B + (size_t)(n0 + row + srow) * K + k0 + scol, Bs + row * 64 + lane * 8);
    }
#else
#pragma unroll
    for (int i = 0; i < 4; i++) {
      int row = wave * 32 + i * 8;
      *(float4*)(As + row * 64 + lane * 8) = *(const float4*)(A + (size_t)(m0 + row + srow) * K + k0 + scol);
      *(float4*)(Bs + row * 64 + lane * 8) = *(const float4*)(B + (size_t)(n0 + row + srow) * K + k0 + scol);
    }
#endif
    __syncthreads();
#pragma unroll
    for (int s = 0; s < 2; s++) {
      bf16x8 af[4], bf[4];
#pragma unroll
      for (int i = 0; i < 4; i++)
        af[i] = *(const bf16x8*)(As + (wm + i * 16 + l15) * 64 + (((s * 4 + quad) ^ (l15 & 7)) * 8));
#pragma unroll
      for (int j = 0; j < 4; j++)
        bf[j] = *(const bf16x8*)(Bs + (wn + j * 16 + l15) * 64 + (((s * 4 + quad) ^ (l15 & 7)) * 8));
#pragma unroll
      for (int i = 0; i < 4; i++)
#pragma unroll
        for (int j = 0; j < 4; j++)
          acc[i][j] = __builtin_amdgcn_mfma_f32_16x16x32_bf16(af[i], bf[j], acc[i][j], 0, 0, 0);
    }
  }
#pragma unroll
  for (int i = 0; i < 4; i++)
#pragma unroll
    for (int j = 0; j < 4; j++)
#pragma unroll
      for (int r = 0; r < 4; r++)
        C[(size_t)(m0 + wm + i * 16 + quad * 4 + r) * N + n0 + wn + j * 16 + l15] = acc[i][j][r];
}

// Fused qkv GEMM (M=4096,N=1536,K=1024) + rope/rms/gate epilogue.
// Wave's 64 cols = head-slot hs: 0-15 Q, 16-19 K, 20-23 V.
// Q scaled 1.2*0.125*log2(e), K 1.2. V += gate*ve, written [b][kh][d][s].
__global__ __launch_bounds__(256) void gemm_qkv_kernel(const unsigned short* __restrict__ A,
                                                       const unsigned short* __restrict__ B,
                                                       const float* __restrict__ ve,
                                                       const float* __restrict__ cosb,
                                                       const float* __restrict__ sinb,
                                                       const float* __restrict__ wgate,
                                                       unsigned short* __restrict__ Q,
                                                       unsigned short* __restrict__ Kd,
                                                       unsigned short* __restrict__ Vt) {
  __shared__ unsigned short As[128 * 64];
  __shared__ unsigned short Bs[128 * 64];
  __shared__ float gLDS[256];
  const int K = 1024;
  int tid = threadIdx.x;
  int wave = tid >> 6, lane = tid & 63, l15 = lane & 15, quad = lane >> 4;
  int wm = (wave >> 1) * 64, wn = (wave & 1) * 64;
  int n0 = blockIdx.x * 128, m0 = blockIdx.y * 128;
  if (n0 >= 1280) {
    int rl = tid & 127, khl2 = tid >> 7;
    int kh = ((n0 >> 6) - 20) + khl2;
    float dot = 0.f;
#pragma unroll
    for (int jj = 0; jj < 12; jj++)
      dot += bf2f(A[(size_t)(m0 + rl) * 1024 + jj]) * wgate[kh * 12 + jj];
    gLDS[khl2 * 128 + rl] = 3.0f / (1.0f + __expf(-dot));
  }
  f32x4 acc[4][4];
#pragma unroll
  for (int i = 0; i < 4; i++)
#pragma unroll
    for (int j = 0; j < 4; j++) acc[i][j] = (f32x4){0.f, 0.f, 0.f, 0.f};
  int srow = lane >> 3;
  int scol = ((lane & 7) ^ srow) * 8;
  for (int k0 = 0; k0 < K; k0 += 64) {
    __syncthreads();
#if HAVE_GLD
#pragma unroll
    for (int i = 0; i < 4; i++) {
      int row = wave * 32 + i * 8;
      gld16(A + (size_t)(m0 + row + srow) * K + k0 + scol, As + row * 64 + lane * 8);
      gld16(B + (size_t)(n0 + row + srow) * K + k0 + scol, Bs + row * 64 + lane * 8);
    }
#else
#pragma unroll
    for (int i = 0; i < 4; i++) {
      int row = wave * 32 + i * 8;
      *(float4*)(As + row * 64 + lane * 8) = *(const float4*)(A + (size_t)(m0 + row + srow) * K + k0 + scol);
      *(float4*)(Bs + row * 64 + lane * 8) = *(const float4*)(B + (size_t)(n0 + row + srow) * K + k0 + scol);
    }
#endif
    __syncthreads();
#pragma unroll
    for (int s = 0; s < 2; s++) {
      bf16x8 af[4], bf[4];
#pragma unroll
      for (int i = 0; i < 4; i++)
        af[i] = *(const bf16x8*)(As + (wm + i * 16 + l15) * 64 + (((s * 4 + quad) ^ (l15 & 7)) * 8));
#pragma unroll
      for (int j = 0; j < 4; j++)
        bf[j] = *(const bf16x8*)(Bs + (wn + j * 16 + l15) * 64 + (((s * 4 + quad) ^ (l15 & 7)) * 8));
#pragma unroll
      for (int i = 0; i < 4; i++)
#pragma unroll
        for (int j = 0; j < 4; j++)
          acc[i][j] = __builtin_amdgcn_mfma_f32_16x16x32_bf16(af[i], bf[j], acc[i][j], 0, 0, 0);
    }
  }
  int hs = (n0 + wn) >> 6;
  if (hs < 20) {
    bool isq = hs < 16;
    float postscale = isq ? 0.216404256f : 1.2f;
#pragma unroll
    for (int i = 0; i < 4; i++) {
#pragma unroll
      for (int r = 0; r < 4; r++) {
        int row = m0 + wm + i * 16 + quad * 4 + r;
        int s = row & 2047, b = row >> 11;
        float c0 = cosb[s * 32 + l15],      s0 = sinb[s * 32 + l15];
        float c1 = cosb[s * 32 + 16 + l15], s1 = sinb[s * 32 + 16 + l15];
        float v0 = acc[i][0][r], v1 = acc[i][1][r], v2 = acc[i][2][r], v3 = acc[i][3][r];
        float n0v = fmaf(v0, c0,  v2 * s0);
        float n1v = fmaf(v1, c1,  v3 * s1);
        float n2v = fmaf(v2, c0, -v0 * s0);
        float n3v = fmaf(v3, c1, -v1 * s1);
        float ss = (n0v * n0v + n1v * n1v) + (n2v * n2v + n3v * n3v);
        ss += __shfl_xor(ss, 1, 64); ss += __shfl_xor(ss, 2, 64);
        ss += __shfl_xor(ss, 4, 64); ss += __shfl_xor(ss, 8, 64);
        float sc = rsqrtf(ss * (1.0f / 64.0f) + 1.1920929e-07f) * postscale;
        unsigned short* dp = isq ? Q + ((size_t)(b * 16 + hs) * 2048 + s) * 64
                                 : Kd + ((size_t)(b * 4 + hs - 16) * 2048 + s) * 64;
        dp[l15]      = f2bf(n0v * sc);
        dp[16 + l15] = f2bf(n1v * sc);
        dp[32 + l15] = f2bf(n2v * sc);
        dp[48 + l15] = f2bf(n3v * sc);
      }
    }
  } else {
    int khl = wave & 1;
    int kh = hs - 20;
#pragma unroll
    for (int i = 0; i < 4; i++) {
#pragma unroll
      for (int r = 0; r < 4; r++) {
        int rl = wm + i * 16 + quad * 4 + r;
        int row = m0 + rl, s = row & 2047, b = row >> 11;
        float g = gLDS[khl * 128 + rl];
        const float* vep = ve + (size_t)row * 256 + kh * 64;
        unsigned short* vp = Vt + ((size_t)(b * 4 + kh) * 64) * 2048 + s;
#pragma unroll
        for (int j = 0; j < 4; j++) {
          float vv = fmaf(g, vep[j * 16 + l15], acc[i][j][r]);
          vp[(size_t)(j * 16 + l15) * 2048] = f2bf(vv);
        }
      }
    }
  }
}

// Causal flash attention, GQA 4:1, HEAD-MERGED (4 Q-heads share one staged K/V stream),
// NO-MAX softmax (exp2-domain partials), split-K x6, double-buffered XOR-swizzled LDS
// with gld16 staging -> ONE barrier per k-tile. Block = (pair, kh, b*6+c).
__global__ __launch_bounds__(256) void flash_kernel(const unsigned short* __restrict__ Q,
                                                    const unsigned short* __restrict__ K,
                                                    const unsigned short* __restrict__ Vt,
                                                    unsigned short* __restrict__ accP,
                                                    float* __restrict__ lP) {
  __shared__ unsigned short Ks[2][64 * 64];      // [buf][key][dim], chunk-swizzled
  __shared__ unsigned short Vs[2][64 * 64];      // [buf][dim][key], chunk-swizzled
  __shared__ unsigned short Ps[4 * 16 * LROW];   // per-wave P [q][key], padded
  int pair = blockIdx.x, kh = blockIdx.y, bc = blockIdx.z;
  int b = bc / NSPLIT, c = bc % NSPLIT;
  int tid = threadIdx.x, wave = tid >> 6, lane = tid & 63, l15 = lane & 15, quad = lane >> 4;
  const unsigned short* Kg = K + (size_t)(b * 4 + kh) * 2048 * 64;
  const unsigned short* Vg = Vt + (size_t)(b * 4 + kh) * 64 * 2048;
  unsigned short* Pw = Ps + wave * 16 * LROW;
  int srow = lane >> 3;                      // staging row-in-8 group
  int scol = ((lane & 7) ^ srow) * 8;        // swizzled source chunk

#pragma unroll
  for (int half = 0; half < 2; half++) {
    int qt = (half == 0) ? pair : 31 - pair;
    int c0t = ((qt + 1) * c) / NSPLIT;
    int c1t = ((qt + 1) * (c + 1)) / NSPLIT;
    int q0 = qt * 64;
    // Q fragments for the 4 heads of this group
    bf16x8 qf[4][2];
#pragma unroll
    for (int h = 0; h < 4; h++) {
      const unsigned short* Qp =
          Q + (((size_t)(b * 16 + kh * 4 + h) * 2048) + q0 + wave * 16 + l15) * 64;
      qf[h][0] = *(const bf16x8*)(Qp + quad * 8);
      qf[h][1] = *(const bf16x8*)(Qp + 32 + quad * 8);
    }
    f32x4 acc[4][4];
#pragma unroll
    for (int h = 0; h < 4; h++)
#pragma unroll
      for (int i = 0; i < 4; i++) acc[h][i] = (f32x4){0.f, 0.f, 0.f, 0.f};
    float l_lane[4] = {0.f, 0.f, 0.f, 0.f};

    if (c1t > c0t) {
      // prologue: stage tile c0t into buf 0 (2 gld16 K + 2 gld16 V per wave)
      {
        int k0 = c0t * 64;
#pragma unroll
        for (int j = 0; j < 2; j++) {
          int row = wave * 16 + j * 8;
#if HAVE_GLD
          gld16(Kg + (size_t)(k0 + row + srow) * 64 + scol, Ks[0] + row * 64 + lane * 8);
          gld16(Vg + (size_t)(row + srow) * 2048 + k0 + scol, Vs[0] + row * 64 + lane * 8);
#else
          *(float4*)(Ks[0] + row * 64 + lane * 8) = *(const float4*)(Kg + (size_t)(k0 + row + srow) * 64 + scol);
          *(float4*)(Vs[0] + row * 64 + lane * 8) = *(const float4*)(Vg + (size_t)(row + srow) * 2048 + k0 + scol);
#endif
        }
      }
      for (int kt = c0t; kt < c1t; kt++) {
        int buf = (kt - c0t) & 1;
        __syncthreads();  // drains prior stage's loads; protects buf^1 reuse
        if (kt + 1 < c1t) {  // async-stage next tile into other buffer
          int kn = (kt + 1) * 64;
#pragma unroll
          for (int j = 0; j < 2; j++) {
            int row = wave * 16 + j * 8;
#if HAVE_GLD
            gld16(Kg + (size_t)(kn + row + srow) * 64 + scol, Ks[buf ^ 1] + row * 64 + lane * 8);
            gld16(Vg + (size_t)(row + srow) * 2048 + kn + scol, Vs[buf ^ 1] + row * 64 + lane * 8);
#else
            *(float4*)(Ks[buf ^ 1] + row * 64 + lane * 8) = *(const float4*)(Kg + (size_t)(kn + row + srow) * 64 + scol);
            *(float4*)(Vs[buf ^ 1] + row * 64 + lane * 8) = *(const float4*)(Vg + (size_t)(row + srow) * 2048 + kn + scol);
#endif
          }
        }
        // K fragments (shared by all 4 heads)
        bf16x8 kf[4][2], vf[4][2];
#pragma unroll
        for (int mt = 0; mt < 4; mt++) {
#pragma unroll
          for (int s2 = 0; s2 < 2; s2++) {
            kf[mt][s2] = *(const bf16x8*)(Ks[buf] + (mt * 16 + l15) * 64 + (((s2 * 4 + quad) ^ (l15 & 7)) * 8));
            vf[mt][s2] = *(const bf16x8*)(Vs[buf] + (mt * 16 + l15) * 64 + (((s2 * 4 + quad) ^ (l15 & 7)) * 8));
          }
        }
        int k0 = kt * 64;
        bool diag = (kt == qt);
        int qg = q0 + wave * 16 + l15;
#pragma unroll
        for (int h = 0; h < 4; h++) {
          // S^T: sv[mt][r] = S[q=l15][key=k0+mt*16+quad*4+r]
          f32x4 sv[4];
#pragma unroll
          for (int mt = 0; mt < 4; mt++) {
            sv[mt] = (f32x4){0.f, 0.f, 0.f, 0.f};
            sv[mt] = __builtin_amdgcn_mfma_f32_16x16x32_bf16(kf[mt][0], qf[h][0], sv[mt], 0, 0, 0);
            sv[mt] = __builtin_amdgcn_mfma_f32_16x16x32_bf16(kf[mt][1], qf[h][1], sv[mt], 0, 0, 0);
          }
          if (diag) {
#pragma unroll
            for (int mt = 0; mt < 4; mt++) {
              int kg = k0 + mt * 16 + quad * 4;
#pragma unroll
              for (int r = 0; r < 4; r++)
                if (kg + r > qg) sv[mt][r] = -1e30f;
            }
          }
#pragma unroll
          for (int mt = 0; mt < 4; mt++) {
            float p0 = __builtin_amdgcn_exp2f(sv[mt][0]);
            float p1 = __builtin_amdgcn_exp2f(sv[mt][1]);
            float p2 = __builtin_amdgcn_exp2f(sv[mt][2]);
            float p3 = __builtin_amdgcn_exp2f(sv[mt][3]);
            l_lane[h] += (p0 + p1) + (p2 + p3);
            unsigned int lo = __builtin_amdgcn_perm(__float_as_uint(p1), __float_as_uint(p0), 0x07060302u);
            unsigned int hi = __builtin_amdgcn_perm(__float_as_uint(p3), __float_as_uint(p2), 0x07060302u);
            *(uint2*)(Pw + l15 * LROW + mt * 16 + quad * 4) = make_uint2(lo, hi);
          }
          // PV (same-wave DS ordering, no barrier)
#pragma unroll
          for (int step = 0; step < 2; step++) {
            bf16x8 pa = *(const bf16x8*)(Pw + l15 * LROW + step * 32 + quad * 8);
#pragma unroll
            for (int nt = 0; nt < 4; nt++)
              acc[h][nt] = __builtin_amdgcn_mfma_f32_16x16x32_bf16(pa, vf[nt][step], acc[h][nt], 0, 0, 0);
          }
        }
      }
    }
#pragma unroll
    for (int h = 0; h < 4; h++) {
      float l = l_lane[h];
      l += __shfl_xor(l, 16, 64);
      l += __shfl_xor(l, 32, 64);
      size_t slot = (size_t)(c * 32 + b * 16 + kh * 4 + h) * 2048 + q0 + wave * 16;
      if (lane < 16) lP[slot + l15] = l;
      unsigned short* aP = accP + slot * 64;
#pragma unroll
      for (int r = 0; r < 4; r++)
#pragma unroll
        for (int nt = 0; nt < 4; nt++)
          aP[(size_t)(quad * 4 + r) * 64 + nt * 16 + l15] = f2bf(acc[h][nt][r]);
    }
  }
}

// merge NSPLIT split-K partials: Y = (Σa_c)/(Σl_c), bf16 out. 4 d-elems/thread.
__global__ __launch_bounds__(256) void merge_kernel(const unsigned short* __restrict__ accP,
                                                    const float* __restrict__ lP,
                                                    unsigned short* __restrict__ Y) {
  int t = blockIdx.x * 256 + threadIdx.x;
  int d4 = (t & 15) * 4;
  int q  = (t >> 4) & 2047;
  int hb = t >> 15;
  const size_t CSTR = (size_t)32 * 2048 * 64;
  size_t pi = ((size_t)hb * 2048 + q) * 64 + d4;
  float y0 = 0.f, y1 = 0.f, y2 = 0.f, y3 = 0.f, l = 0.f;
#pragma unroll
  for (int c = 0; c < NSPLIT; c++) {
    ushort4 a = *(const ushort4*)(accP + pi + c * CSTR);
    y0 += bf2f(a.x); y1 += bf2f(a.y); y2 += bf2f(a.z); y3 += bf2f(a.w);
    l += lP[c * 65536 + hb * 2048 + q];
  }
  float inv = 1.f / l;
  ushort4 o;
  o.x = f2bf(y0 * inv); o.y = f2bf(y1 * inv); o.z = f2bf(y2 * inv); o.w = f2bf(y3 * inv);
  int b = hb >> 4, hh = hb & 15;
  *(ushort4*)(Y + ((size_t)(b * 2048 + q) * 1024) + hh * 64 + d4) = o;
}

extern "C" void kernel_launch(void* const* d_in, const int* in_sizes, int n_in,
                              void* d_out, int out_size, void* d_ws, size_t ws_size,
                              hipStream_t stream) {
  const float* x     = (const float*)d_in[0];
  const float* ve    = (const float*)d_in[1];
  const float* cosb  = (const float*)d_in[2];
  const float* sinb  = (const float*)d_in[3];
  // d_in[4] attn_mask: causal, hard-coded
  const float* Wq    = (const float*)d_in[5];
  const float* Wk    = (const float*)d_in[6];
  const float* Wv    = (const float*)d_in[7];
  const float* Wproj = (const float*)d_in[8];
  const float* Wgate = (const float*)d_in[9];
  float* out = (float*)d_out;
  char* ws = (char*)d_ws;

  size_t o = 0;
  unsigned short* xb   = (unsigned short*)(ws + o); o += (size_t)4096 * 1024 * 2;
  unsigned short* wqkv = (unsigned short*)(ws + o); o += (size_t)1536 * 1024 * 2;
  unsigned short* wpj  = (unsigned short*)(ws + o); o += (size_t)1024 * 1024 * 2;
  unsigned short* Qb   = (unsigned short*)(ws + o); o += (size_t)2 * 16 * 2048 * 64 * 2;
  unsigned short* Kb   = (unsigned short*)(ws + o); o += (size_t)2 * 4 * 2048 * 64 * 2;
  unsigned short* Vb   = (unsigned short*)(ws + o); o += (size_t)2 * 4 * 2048 * 64 * 2; // [b][kh][d][s]
  unsigned short* Yb   = (unsigned short*)(ws + o); o += (size_t)4096 * 1024 * 2;
  unsigned short* accP = (unsigned short*)(ws + o); o += (size_t)NSPLIT * 32 * 2048 * 64 * 2;
  float*          lP   = (float*)(ws + o);          o += (size_t)NSPLIT * 32 * 2048 * 4;

  hipLaunchKernelGGL(cvt_all_kernel, dim3(6656), dim3(256), 0, stream,
                     x, Wq, Wk, Wv, Wproj, xb, wqkv, wpj);
  hipLaunchKernelGGL(gemm_qkv_kernel, dim3(12, 32), dim3(256), 0, stream,
                     xb, wqkv, ve, cosb, sinb, Wgate, Qb, Kb, Vb);
  hipLaunchKernelGGL(flash_kernel, dim3(16, 4, 2 * NSPLIT), dim3(256), 0, stream,
                     Qb, Kb, Vb, accP, lP);
  hipLaunchKernelGGL(merge_kernel, dim3(4096), dim3(256), 0, stream, accP, lP, Yb);
  hipLaunchKernelGGL(gemm128_kernel, dim3(8, 32), dim3(256), 0, stream, Yb, wpj, out, 4096, 1024, 1024);
}

// Round 8
// 211.410 us; speedup vs baseline: 1.0604x; 1.0604x over previous
//
#include <hip/hip_runtime.h>
#include <hip/hip_bf16.h>
#include <math.h>

typedef short bf16x8 __attribute__((ext_vector_type(8)));
typedef float f32x4 __attribute__((ext_vector_type(4)));

#define LROW 72   // padded LDS row for P (bf16 elems): 2-way alias, free

__device__ __forceinline__ unsigned short f2bf(float f) {
  union { float f; unsigned int u; } v; v.f = f;
  unsigned int u = v.u;
  unsigned int r = (u + 0x7fffu + ((u >> 16) & 1u)) >> 16;
  return (unsigned short)r;
}
__device__ __forceinline__ float bf2f(unsigned short u) {
  return __uint_as_float((unsigned)u << 16);
}

#if __has_builtin(__builtin_amdgcn_global_load_lds)
#define HAVE_GLD 1
__device__ __forceinline__ void gld16(const void* g, void* l) {
  __builtin_amdgcn_global_load_lds(
      (const __attribute__((address_space(1))) unsigned int*)g,
      (__attribute__((address_space(3))) unsigned int*)l, 16, 0, 0);
}
#else
#define HAVE_GLD 0
#endif

// All fp32->bf16 converts: x (4096 blk), Wq(1024), Wk(256), Wv(256), Wproj(1024)
__global__ __launch_bounds__(256) void cvt_all_kernel(const float* __restrict__ x,
                                                      const float* __restrict__ Wq,
                                                      const float* __restrict__ Wk,
                                                      const float* __restrict__ Wv,
                                                      const float* __restrict__ Wproj,
                                                      unsigned short* __restrict__ xb,
                                                      unsigned short* __restrict__ wqkv,
                                                      unsigned short* __restrict__ wpj) {
  int blk = blockIdx.x;
  const float* src;
  unsigned short* dst;
  if (blk < 4096)      { src = x + (size_t)blk * 1024;            dst = xb + (size_t)blk * 1024; }
  else if (blk < 5120) { src = Wq + (size_t)(blk - 4096) * 1024;  dst = wqkv + (size_t)(blk - 4096) * 1024; }
  else if (blk < 5376) { src = Wk + (size_t)(blk - 5120) * 1024;  dst = wqkv + (size_t)(blk - 4096) * 1024; }
  else if (blk < 5632) { src = Wv + (size_t)(blk - 5376) * 1024;  dst = wqkv + (size_t)(blk - 4096) * 1024; }
  else                 { src = Wproj + (size_t)(blk - 5632) * 1024; dst = wpj + (size_t)(blk - 5632) * 1024; }
  int i = threadIdx.x;
  float4 v = ((const float4*)src)[i];
  ushort4 o;
  o.x = f2bf(v.x); o.y = f2bf(v.y); o.z = f2bf(v.z); o.w = f2bf(v.w);
  ((ushort4*)dst)[i] = o;
}

// Fused qkv GEMM (M=4096,N=1536,K=1024) + rope/rms/gate epilogue.
// Wave's 64 cols = head-slot hs: 0-15 Q, 16-19 K, 20-23 V.
// Q scaled 1.2*0.125*log2(e), K 1.2. V += gate*ve, written [b][kh][d][s].
__global__ __launch_bounds__(256) void gemm_qkv_kernel(const unsigned short* __restrict__ A,
                                                       const unsigned short* __restrict__ B,
                                                       const float* __restrict__ ve,
                                                       const float* __restrict__ cosb,
                                                       const float* __restrict__ sinb,
                                                       const float* __restrict__ wgate,
                                                       unsigned short* __restrict__ Q,
                                                       unsigned short* __restrict__ Kd,
                                                       unsigned short* __restrict__ Vt) {
  __shared__ unsigned short As[128 * 64];
  __shared__ unsigned short Bs[128 * 64];
  __shared__ float gLDS[256];
  const int K = 1024;
  int tid = threadIdx.x;
  int wave = tid >> 6, lane = tid & 63, l15 = lane & 15, quad = lane >> 4;
  int wm = (wave >> 1) * 64, wn = (wave & 1) * 64;
  int n0 = blockIdx.x * 128, m0 = blockIdx.y * 128;
  if (n0 >= 1280) {
    int rl = tid & 127, khl2 = tid >> 7;
    int kh = ((n0 >> 6) - 20) + khl2;
    float dot = 0.f;
#pragma unroll
    for (int jj = 0; jj < 12; jj++)
      dot += bf2f(A[(size_t)(m0 + rl) * 1024 + jj]) * wgate[kh * 12 + jj];
    gLDS[khl2 * 128 + rl] = 3.0f / (1.0f + __expf(-dot));
  }
  f32x4 acc[4][4];
#pragma unroll
  for (int i = 0; i < 4; i++)
#pragma unroll
    for (int j = 0; j < 4; j++) acc[i][j] = (f32x4){0.f, 0.f, 0.f, 0.f};
  int srow = lane >> 3;
  int scol = ((lane & 7) ^ srow) * 8;
  for (int k0 = 0; k0 < K; k0 += 64) {
    __syncthreads();
#if HAVE_GLD
#pragma unroll
    for (int i = 0; i < 4; i++) {
      int row = wave * 32 + i * 8;
      gld16(A + (size_t)(m0 + row + srow) * K + k0 + scol, As + row * 64 + lane * 8);
      gld16(B + (size_t)(n0 + row + srow) * K + k0 + scol, Bs + row * 64 + lane * 8);
    }
#else
#pragma unroll
    for (int i = 0; i < 4; i++) {
      int row = wave * 32 + i * 8;
      *(float4*)(As + row * 64 + lane * 8) = *(const float4*)(A + (size_t)(m0 + row + srow) * K + k0 + scol);
      *(float4*)(Bs + row * 64 + lane * 8) = *(const float4*)(B + (size_t)(n0 + row + srow) * K + k0 + scol);
    }
#endif
    __syncthreads();
#pragma unroll
    for (int s = 0; s < 2; s++) {
      bf16x8 af[4], bf[4];
#pragma unroll
      for (int i = 0; i < 4; i++)
        af[i] = *(const bf16x8*)(As + (wm + i * 16 + l15) * 64 + (((s * 4 + quad) ^ (l15 & 7)) * 8));
#pragma unroll
      for (int j = 0; j < 4; j++)
        bf[j] = *(const bf16x8*)(Bs + (wn + j * 16 + l15) * 64 + (((s * 4 + quad) ^ (l15 & 7)) * 8));
#pragma unroll
      for (int i = 0; i < 4; i++)
#pragma unroll
        for (int j = 0; j < 4; j++)
          acc[i][j] = __builtin_amdgcn_mfma_f32_16x16x32_bf16(af[i], bf[j], acc[i][j], 0, 0, 0);
    }
  }
  int hs = (n0 + wn) >> 6;
  if (hs < 20) {
    bool isq = hs < 16;
    float postscale = isq ? 0.216404256f : 1.2f;
#pragma unroll
    for (int i = 0; i < 4; i++) {
#pragma unroll
      for (int r = 0; r < 4; r++) {
        int row = m0 + wm + i * 16 + quad * 4 + r;
        int s = row & 2047, b = row >> 11;
        float c0 = cosb[s * 32 + l15],      s0 = sinb[s * 32 + l15];
        float c1 = cosb[s * 32 + 16 + l15], s1 = sinb[s * 32 + 16 + l15];
        float v0 = acc[i][0][r], v1 = acc[i][1][r], v2 = acc[i][2][r], v3 = acc[i][3][r];
        float n0v = fmaf(v0, c0,  v2 * s0);
        float n1v = fmaf(v1, c1,  v3 * s1);
        float n2v = fmaf(v2, c0, -v0 * s0);
        float n3v = fmaf(v3, c1, -v1 * s1);
        float ss = (n0v * n0v + n1v * n1v) + (n2v * n2v + n3v * n3v);
        ss += __shfl_xor(ss, 1, 64); ss += __shfl_xor(ss, 2, 64);
        ss += __shfl_xor(ss, 4, 64); ss += __shfl_xor(ss, 8, 64);
        float sc = rsqrtf(ss * (1.0f / 64.0f) + 1.1920929e-07f) * postscale;
        unsigned short* dp = isq ? Q + ((size_t)(b * 16 + hs) * 2048 + s) * 64
                                 : Kd + ((size_t)(b * 4 + hs - 16) * 2048 + s) * 64;
        dp[l15]      = f2bf(n0v * sc);
        dp[16 + l15] = f2bf(n1v * sc);
        dp[32 + l15] = f2bf(n2v * sc);
        dp[48 + l15] = f2bf(n3v * sc);
      }
    }
  } else {
    int khl = wave & 1;
    int kh = hs - 20;
#pragma unroll
    for (int i = 0; i < 4; i++) {
#pragma unroll
      for (int r = 0; r < 4; r++) {
        int rl = wm + i * 16 + quad * 4 + r;
        int row = m0 + rl, s = row & 2047, b = row >> 11;
        float g = gLDS[khl * 128 + rl];
        const float* vep = ve + (size_t)row * 256 + kh * 64;
        unsigned short* vp = Vt + ((size_t)(b * 4 + kh) * 64) * 2048 + s;
#pragma unroll
        for (int j = 0; j < 4; j++) {
          float vv = fmaf(g, vep[j * 16 + l15], acc[i][j][r]);
          vp[(size_t)(j * 16 + l15) * 2048] = f2bf(vv);
        }
      }
    }
  }
}

// Causal flash attention, GQA 4:1, NO-MAX softmax (exp2-domain partials), split-K x2,
// PER-HEAD blocks (low VGPR), gld16 + double-buffer + XOR-swizzle staging ->
// ONE barrier per k-tile, conflict-free LDS. Block = (pair, h, b*2+c).
__global__ __launch_bounds__(256) void flash_kernel(const unsigned short* __restrict__ Q,
                                                    const unsigned short* __restrict__ K,
                                                    const unsigned short* __restrict__ Vt,
                                                    unsigned short* __restrict__ accP,
                                                    float* __restrict__ lP) {
  __shared__ unsigned short Ks[2][64 * 64];      // [buf][key][dim], chunk-swizzled
  __shared__ unsigned short Vs[2][64 * 64];      // [buf][dim][key], chunk-swizzled
  __shared__ unsigned short Ps[4 * 16 * LROW];   // per-wave P [q][key], padded
  int pair = blockIdx.x, h = blockIdx.y, bc = blockIdx.z;
  int b = bc >> 1, c = bc & 1;
  int hb = b * 16 + h;
  int kh = h >> 2;
  int tid = threadIdx.x, wave = tid >> 6, lane = tid & 63, l15 = lane & 15, quad = lane >> 4;
  const unsigned short* Kg = K + (size_t)(b * 4 + kh) * 2048 * 64;
  const unsigned short* Vg = Vt + (size_t)(b * 4 + kh) * 64 * 2048;
  unsigned short* Pw = Ps + wave * 16 * LROW;
  int srow = lane >> 3;                      // staging row within 8-group
  int scol = ((lane & 7) ^ srow) * 8;        // swizzled source chunk

#pragma unroll
  for (int half = 0; half < 2; half++) {
    int qt = (half == 0) ? pair : 31 - pair;
    int c0t = (c == 0) ? 0 : (qt + 2) >> 1;       // chunk key-tile range [c0t, c1t)
    int c1t = (c == 0) ? ((qt + 2) >> 1) : qt + 1;
    int q0 = qt * 64;
    const unsigned short* Qp = Q + (((size_t)hb * 2048) + q0 + wave * 16 + l15) * 64;
    bf16x8 qf0 = *(const bf16x8*)(Qp + quad * 8);
    bf16x8 qf1 = *(const bf16x8*)(Qp + 32 + quad * 8);
    f32x4 acc[4];
#pragma unroll
    for (int i = 0; i < 4; i++) acc[i] = (f32x4){0.f, 0.f, 0.f, 0.f};
    float l_lane = 0.f;

    if (c1t > c0t) {
      {  // prologue: stage tile c0t into buf 0
        int k0 = c0t * 64;
#pragma unroll
        for (int j = 0; j < 2; j++) {
          int row = wave * 16 + j * 8;
#if HAVE_GLD
          gld16(Kg + (size_t)(k0 + row + srow) * 64 + scol, Ks[0] + row * 64 + lane * 8);
          gld16(Vg + (size_t)(row + srow) * 2048 + k0 + scol, Vs[0] + row * 64 + lane * 8);
#else
          *(float4*)(Ks[0] + row * 64 + lane * 8) = *(const float4*)(Kg + (size_t)(k0 + row + srow) * 64 + scol);
          *(float4*)(Vs[0] + row * 64 + lane * 8) = *(const float4*)(Vg + (size_t)(row + srow) * 2048 + k0 + scol);
#endif
        }
      }
      for (int kt = c0t; kt < c1t; kt++) {
        int buf = (kt - c0t) & 1;
        __syncthreads();  // drains in-flight stage for tile kt; protects buf^1 reuse
        if (kt + 1 < c1t) {  // stage next tile into other buffer (overlaps compute)
          int kn = (kt + 1) * 64;
#pragma unroll
          for (int j = 0; j < 2; j++) {
            int row = wave * 16 + j * 8;
#if HAVE_GLD
            gld16(Kg + (size_t)(kn + row + srow) * 64 + scol, Ks[buf ^ 1] + row * 64 + lane * 8);
            gld16(Vg + (size_t)(row + srow) * 2048 + kn + scol, Vs[buf ^ 1] + row * 64 + lane * 8);
#else
            *(float4*)(Ks[buf ^ 1] + row * 64 + lane * 8) = *(const float4*)(Kg + (size_t)(kn + row + srow) * 64 + scol);
            *(float4*)(Vs[buf ^ 1] + row * 64 + lane * 8) = *(const float4*)(Vg + (size_t)(row + srow) * 2048 + kn + scol);
#endif
          }
        }
        int k0 = kt * 64;
        // S^T: sv[mt][r] = S[q=l15][key=k0+mt*16+quad*4+r]
        f32x4 sv[4];
#pragma unroll
        for (int mt = 0; mt < 4; mt++) {
          sv[mt] = (f32x4){0.f, 0.f, 0.f, 0.f};
          bf16x8 k0f = *(const bf16x8*)(Ks[buf] + (mt * 16 + l15) * 64 + ((quad ^ (l15 & 7)) * 8));
          sv[mt] = __builtin_amdgcn_mfma_f32_16x16x32_bf16(k0f, qf0, sv[mt], 0, 0, 0);
          bf16x8 k1f = *(const bf16x8*)(Ks[buf] + (mt * 16 + l15) * 64 + (((4 + quad) ^ (l15 & 7)) * 8));
          sv[mt] = __builtin_amdgcn_mfma_f32_16x16x32_bf16(k1f, qf1, sv[mt], 0, 0, 0);
        }
        if (kt == qt) {  // diagonal: causal mask (key > q)
          int qg = q0 + wave * 16 + l15;
#pragma unroll
          for (int mt = 0; mt < 4; mt++) {
            int kg = k0 + mt * 16 + quad * 4;
#pragma unroll
            for (int r = 0; r < 4; r++)
              if (kg + r > qg) sv[mt][r] = -1e30f;
          }
        }
#pragma unroll
        for (int mt = 0; mt < 4; mt++) {
          float p0 = __builtin_amdgcn_exp2f(sv[mt][0]);
          float p1 = __builtin_amdgcn_exp2f(sv[mt][1]);
          float p2 = __builtin_amdgcn_exp2f(sv[mt][2]);
          float p3 = __builtin_amdgcn_exp2f(sv[mt][3]);
          l_lane += (p0 + p1) + (p2 + p3);
          unsigned int lo = __builtin_amdgcn_perm(__float_as_uint(p1), __float_as_uint(p0), 0x07060302u);
          unsigned int hi = __builtin_amdgcn_perm(__float_as_uint(p3), __float_as_uint(p2), 0x07060302u);
          *(uint2*)(Pw + l15 * LROW + mt * 16 + quad * 4) = make_uint2(lo, hi);
        }
        // PV: A = P rows (q=l15), B = V^T fragments. Same-wave DS ordering, no barrier.
#pragma unroll
        for (int step = 0; step < 2; step++) {
          bf16x8 pa = *(const bf16x8*)(Pw + l15 * LROW + step * 32 + quad * 8);
#pragma unroll
          for (int nt = 0; nt < 4; nt++) {
            bf16x8 vb = *(const bf16x8*)(Vs[buf] + (nt * 16 + l15) * 64 + (((step * 4 + quad) ^ (l15 & 7)) * 8));
            acc[nt] = __builtin_amdgcn_mfma_f32_16x16x32_bf16(pa, vb, acc[nt], 0, 0, 0);
          }
        }
      }
    }
    l_lane += __shfl_xor(l_lane, 16, 64);
    l_lane += __shfl_xor(l_lane, 32, 64);

    size_t slot = (size_t)(c * 32 + hb) * 2048 + q0 + wave * 16;
    if (lane < 16) lP[slot + l15] = l_lane;
    unsigned short* aP = accP + slot * 64;
#pragma unroll
    for (int r = 0; r < 4; r++)
#pragma unroll
      for (int nt = 0; nt < 4; nt++)
        aP[(size_t)(quad * 4 + r) * 64 + nt * 16 + l15] = f2bf(acc[nt][r]);
  }
}

// Proj GEMM with FUSED split-K merge: out[M=4096][N=1024] = Y x Wproj^T where
// Y = (acc_c0 + acc_c1) / (l_c0 + l_c1) is computed on the fly during A-staging
// (each BK=64 k-slice is exactly one head h = k0>>6). B staged via gld16.
__global__ __launch_bounds__(256) void gemm_proj_kernel(const unsigned short* __restrict__ accP,
                                                        const float* __restrict__ lP,
                                                        const unsigned short* __restrict__ B,
                                                        float* __restrict__ C) {
  __shared__ unsigned short As[128 * 64];
  __shared__ unsigned short Bs[128 * 64];
  const int K = 1024, N = 1024;
  const size_t CSTR = (size_t)32 * 2048 * 64;
  int tid = threadIdx.x;
  int wave = tid >> 6, lane = tid & 63, l15 = lane & 15, quad = lane >> 4;
  int wm = (wave >> 1) * 64, wn = (wave & 1) * 64;
  int n0 = blockIdx.x * 128, m0 = blockIdx.y * 128;
  f32x4 acc[4][4];
#pragma unroll
  for (int i = 0; i < 4; i++)
#pragma unroll
    for (int j = 0; j < 4; j++) acc[i][j] = (f32x4){0.f, 0.f, 0.f, 0.f};
  int srow = lane >> 3;
  int scol = ((lane & 7) ^ srow) * 8;
  for (int k0 = 0; k0 < K; k0 += 64) {
    int h = k0 >> 6;
    __syncthreads();
#pragma unroll
    for (int i = 0; i < 4; i++) {
      int row = wave * 32 + i * 8;
#if HAVE_GLD
      gld16(B + (size_t)(n0 + row + srow) * K + k0 + scol, Bs + row * 64 + lane * 8);
#else
      *(float4*)(Bs + row * 64 + lane * 8) = *(const float4*)(B + (size_t)(n0 + row + srow) * K + k0 + scol);
#endif
      // A-staging with fused merge: token gr, head h, dims scol..scol+7
      int gr = m0 + row + srow;
      int q = gr & 2047, bb = gr >> 11;
      size_t base = ((size_t)((bb * 16 + h) * 2048) + q) * 64 + scol;
      uint4 a0 = *(const uint4*)(accP + base);
      uint4 a1 = *(const uint4*)(accP + base + CSTR);
      float inv = 1.f / (lP[(bb * 16 + h) * 2048 + q] + lP[65536 + (bb * 16 + h) * 2048 + q]);
      unsigned int w[4];
#pragma unroll
      for (int e = 0; e < 4; e++) {
        unsigned int u0 = ((const unsigned int*)&a0)[e];
        unsigned int u1 = ((const unsigned int*)&a1)[e];
        float lo = (__uint_as_float(u0 << 16) + __uint_as_float(u1 << 16)) * inv;
        float hi = (__uint_as_float(u0 & 0xffff0000u) + __uint_as_float(u1 & 0xffff0000u)) * inv;
        w[e] = ((unsigned int)f2bf(lo)) | (((unsigned int)f2bf(hi)) << 16);
      }
      *(uint4*)(As + row * 64 + lane * 8) = make_uint4(w[0], w[1], w[2], w[3]);
    }
    __syncthreads();
#pragma unroll
    for (int s = 0; s < 2; s++) {
      bf16x8 af[4], bf[4];
#pragma unroll
      for (int i = 0; i < 4; i++)
        af[i] = *(const bf16x8*)(As + (wm + i * 16 + l15) * 64 + (((s * 4 + quad) ^ (l15 & 7)) * 8));
#pragma unroll
      for (int j = 0; j < 4; j++)
        bf[j] = *(const bf16x8*)(Bs + (wn + j * 16 + l15) * 64 + (((s * 4 + quad) ^ (l15 & 7)) * 8));
#pragma unroll
      for (int i = 0; i < 4; i++)
#pragma unroll
        for (int j = 0; j < 4; j++)
          acc[i][j] = __builtin_amdgcn_mfma_f32_16x16x32_bf16(af[i], bf[j], acc[i][j], 0, 0, 0);
    }
  }
#pragma unroll
  for (int i = 0; i < 4; i++)
#pragma unroll
    for (int j = 0; j < 4; j++)
#pragma unroll
      for (int r = 0; r < 4; r++)
        C[(size_t)(m0 + wm + i * 16 + quad * 4 + r) * N + n0 + wn + j * 16 + l15] = acc[i][j][r];
}

extern "C" void kernel_launch(void* const* d_in, const int* in_sizes, int n_in,
                              void* d_out, int out_size, void* d_ws, size_t ws_size,
                              hipStream_t stream) {
  const float* x     = (const float*)d_in[0];
  const float* ve    = (const float*)d_in[1];
  const float* cosb  = (const float*)d_in[2];
  const float* sinb  = (const float*)d_in[3];
  // d_in[4] attn_mask: causal, hard-coded
  const float* Wq    = (const float*)d_in[5];
  const float* Wk    = (const float*)d_in[6];
  const float* Wv    = (const float*)d_in[7];
  const float* Wproj = (const float*)d_in[8];
  const float* Wgate = (const float*)d_in[9];
  float* out = (float*)d_out;
  char* ws = (char*)d_ws;

  size_t o = 0;
  unsigned short* xb   = (unsigned short*)(ws + o); o += (size_t)4096 * 1024 * 2;
  unsigned short* wqkv = (unsigned short*)(ws + o); o += (size_t)1536 * 1024 * 2;
  unsigned short* wpj  = (unsigned short*)(ws + o); o += (size_t)1024 * 1024 * 2;
  unsigned short* Qb   = (unsigned short*)(ws + o); o += (size_t)2 * 16 * 2048 * 64 * 2;
  unsigned short* Kb   = (unsigned short*)(ws + o); o += (size_t)2 * 4 * 2048 * 64 * 2;
  unsigned short* Vb   = (unsigned short*)(ws + o); o += (size_t)2 * 4 * 2048 * 64 * 2; // [b][kh][d][s]
  unsigned short* accP = (unsigned short*)(ws + o); o += (size_t)2 * 32 * 2048 * 64 * 2;
  float*          lP   = (float*)(ws + o);          o += (size_t)2 * 32 * 2048 * 4;

  hipLaunchKernelGGL(cvt_all_kernel, dim3(6656), dim3(256), 0, stream,
                     x, Wq, Wk, Wv, Wproj, xb, wqkv, wpj);
  hipLaunchKernelGGL(gemm_qkv_kernel, dim3(12, 32), dim3(256), 0, stream,
                     xb, wqkv, ve, cosb, sinb, Wgate, Qb, Kb, Vb);
  hipLaunchKernelGGL(flash_kernel, dim3(16, 16, 4), dim3(256), 0, stream, Qb, Kb, Vb, accP, lP);
  hipLaunchKernelGGL(gemm_proj_kernel, dim3(8, 32), dim3(256), 0, stream, accP, lP, wpj, out);
}

// Round 9
// 206.331 us; speedup vs baseline: 1.0865x; 1.0246x over previous
//
#include <hip/hip_runtime.h>
#include <hip/hip_bf16.h>
#include <math.h>

typedef short bf16x8 __attribute__((ext_vector_type(8)));
typedef float f32x4 __attribute__((ext_vector_type(4)));

#define LROW 72   // padded LDS row for P (bf16 elems): 2-way alias, free
#define NSPLIT 4  // flash split-K chunks

__device__ __forceinline__ unsigned short f2bf(float f) {
  union { float f; unsigned int u; } v; v.f = f;
  unsigned int u = v.u;
  unsigned int r = (u + 0x7fffu + ((u >> 16) & 1u)) >> 16;
  return (unsigned short)r;
}
__device__ __forceinline__ float bf2f(unsigned short u) {
  return __uint_as_float((unsigned)u << 16);
}

#if __has_builtin(__builtin_amdgcn_global_load_lds)
#define HAVE_GLD 1
__device__ __forceinline__ void gld16(const void* g, void* l) {
  __builtin_amdgcn_global_load_lds(
      (const __attribute__((address_space(1))) unsigned int*)g,
      (__attribute__((address_space(3))) unsigned int*)l, 16, 0, 0);
}
#else
#define HAVE_GLD 0
#endif

// All fp32->bf16 converts: x (4096 blk), Wq(1024), Wk(256), Wv(256), Wproj(1024)
__global__ __launch_bounds__(256) void cvt_all_kernel(const float* __restrict__ x,
                                                      const float* __restrict__ Wq,
                                                      const float* __restrict__ Wk,
                                                      const float* __restrict__ Wv,
                                                      const float* __restrict__ Wproj,
                                                      unsigned short* __restrict__ xb,
                                                      unsigned short* __restrict__ wqkv,
                                                      unsigned short* __restrict__ wpj) {
  int blk = blockIdx.x;
  const float* src;
  unsigned short* dst;
  if (blk < 4096)      { src = x + (size_t)blk * 1024;            dst = xb + (size_t)blk * 1024; }
  else if (blk < 5120) { src = Wq + (size_t)(blk - 4096) * 1024;  dst = wqkv + (size_t)(blk - 4096) * 1024; }
  else if (blk < 5376) { src = Wk + (size_t)(blk - 5120) * 1024;  dst = wqkv + (size_t)(blk - 4096) * 1024; }
  else if (blk < 5632) { src = Wv + (size_t)(blk - 5376) * 1024;  dst = wqkv + (size_t)(blk - 4096) * 1024; }
  else                 { src = Wproj + (size_t)(blk - 5632) * 1024; dst = wpj + (size_t)(blk - 5632) * 1024; }
  int i = threadIdx.x;
  float4 v = ((const float4*)src)[i];
  ushort4 o;
  o.x = f2bf(v.x); o.y = f2bf(v.y); o.z = f2bf(v.z); o.w = f2bf(v.w);
  ((ushort4*)dst)[i] = o;
}

// Plain GEMM C[M][N] = A[M][K] x B[N][K]^T; 128x128 tile, BK=64, gld16 staging, XOR swizzle.
__global__ __launch_bounds__(256) void gemm128_kernel(const unsigned short* __restrict__ A,
                                                      const unsigned short* __restrict__ B,
                                                      float* __restrict__ C, int M, int N, int K) {
  __shared__ unsigned short As[128 * 64];
  __shared__ unsigned short Bs[128 * 64];
  int tid = threadIdx.x;
  int wave = tid >> 6, lane = tid & 63, l15 = lane & 15, quad = lane >> 4;
  int wm = (wave >> 1) * 64, wn = (wave & 1) * 64;
  int n0 = blockIdx.x * 128, m0 = blockIdx.y * 128;
  f32x4 acc[4][4];
#pragma unroll
  for (int i = 0; i < 4; i++)
#pragma unroll
    for (int j = 0; j < 4; j++) acc[i][j] = (f32x4){0.f, 0.f, 0.f, 0.f};
  int srow = lane >> 3;
  int scol = ((lane & 7) ^ srow) * 8;
  for (int k0 = 0; k0 < K; k0 += 64) {
    __syncthreads();
#if HAVE_GLD
#pragma unroll
    for (int i = 0; i < 4; i++) {
      int row = wave * 32 + i * 8;
      gld16(A + (size_t)(m0 + row + srow) * K + k0 + scol, As + row * 64 + lane * 8);
      gld16(B + (size_t)(n0 + row + srow) * K + k0 + scol, Bs + row * 64 + lane * 8);
    }
#else
#pragma unroll
    for (int i = 0; i < 4; i++) {
      int row = wave * 32 + i * 8;
      *(float4*)(As + row * 64 + lane * 8) = *(const float4*)(A + (size_t)(m0 + row + srow) * K + k0 + scol);
      *(float4*)(Bs + row * 64 + lane * 8) = *(const float4*)(B + (size_t)(n0 + row + srow) * K + k0 + scol);
    }
#endif
    __syncthreads();
#pragma unroll
    for (int s = 0; s < 2; s++) {
      bf16x8 af[4], bf[4];
#pragma unroll
      for (int i = 0; i < 4; i++)
        af[i] = *(const bf16x8*)(As + (wm + i * 16 + l15) * 64 + (((s * 4 + quad) ^ (l15 & 7)) * 8));
#pragma unroll
      for (int j = 0; j < 4; j++)
        bf[j] = *(const bf16x8*)(Bs + (wn + j * 16 + l15) * 64 + (((s * 4 + quad) ^ (l15 & 7)) * 8));
#pragma unroll
      for (int i = 0; i < 4; i++)
#pragma unroll
        for (int j = 0; j < 4; j++)
          acc[i][j] = __builtin_amdgcn_mfma_f32_16x16x32_bf16(af[i], bf[j], acc[i][j], 0, 0, 0);
    }
  }
#pragma unroll
  for (int i = 0; i < 4; i++)
#pragma unroll
    for (int j = 0; j < 4; j++)
#pragma unroll
      for (int r = 0; r < 4; r++)
        C[(size_t)(m0 + wm + i * 16 + quad * 4 + r) * N + n0 + wn + j * 16 + l15] = acc[i][j][r];
}

// Fused qkv GEMM (M=4096,N=1536,K=1024) + rope/rms/gate epilogue.
// Wave's 64 cols = head-slot hs: 0-15 Q, 16-19 K, 20-23 V.
// Q scaled 1.2*0.125*log2(e), K 1.2. V += gate*ve, written [b][kh][d][s].
__global__ __launch_bounds__(256) void gemm_qkv_kernel(const unsigned short* __restrict__ A,
                                                       const unsigned short* __restrict__ B,
                                                       const float* __restrict__ ve,
                                                       const float* __restrict__ cosb,
                                                       const float* __restrict__ sinb,
                                                       const float* __restrict__ wgate,
                                                       unsigned short* __restrict__ Q,
                                                       unsigned short* __restrict__ Kd,
                                                       unsigned short* __restrict__ Vt) {
  __shared__ unsigned short As[128 * 64];
  __shared__ unsigned short Bs[128 * 64];
  __shared__ float gLDS[256];
  const int K = 1024;
  int tid = threadIdx.x;
  int wave = tid >> 6, lane = tid & 63, l15 = lane & 15, quad = lane >> 4;
  int wm = (wave >> 1) * 64, wn = (wave & 1) * 64;
  int n0 = blockIdx.x * 128, m0 = blockIdx.y * 128;
  if (n0 >= 1280) {
    int rl = tid & 127, khl2 = tid >> 7;
    int kh = ((n0 >> 6) - 20) + khl2;
    float dot = 0.f;
#pragma unroll
    for (int jj = 0; jj < 12; jj++)
      dot += bf2f(A[(size_t)(m0 + rl) * 1024 + jj]) * wgate[kh * 12 + jj];
    gLDS[khl2 * 128 + rl] = 3.0f / (1.0f + __expf(-dot));
  }
  f32x4 acc[4][4];
#pragma unroll
  for (int i = 0; i < 4; i++)
#pragma unroll
    for (int j = 0; j < 4; j++) acc[i][j] = (f32x4){0.f, 0.f, 0.f, 0.f};
  int srow = lane >> 3;
  int scol = ((lane & 7) ^ srow) * 8;
  for (int k0 = 0; k0 < K; k0 += 64) {
    __syncthreads();
#if HAVE_GLD
#pragma unroll
    for (int i = 0; i < 4; i++) {
      int row = wave * 32 + i * 8;
      gld16(A + (size_t)(m0 + row + srow) * K + k0 + scol, As + row * 64 + lane * 8);
      gld16(B + (size_t)(n0 + row + srow) * K + k0 + scol, Bs + row * 64 + lane * 8);
    }
#else
#pragma unroll
    for (int i = 0; i < 4; i++) {
      int row = wave * 32 + i * 8;
      *(float4*)(As + row * 64 + lane * 8) = *(const float4*)(A + (size_t)(m0 + row + srow) * K + k0 + scol);
      *(float4*)(Bs + row * 64 + lane * 8) = *(const float4*)(B + (size_t)(n0 + row + srow) * K + k0 + scol);
    }
#endif
    __syncthreads();
#pragma unroll
    for (int s = 0; s < 2; s++) {
      bf16x8 af[4], bf[4];
#pragma unroll
      for (int i = 0; i < 4; i++)
        af[i] = *(const bf16x8*)(As + (wm + i * 16 + l15) * 64 + (((s * 4 + quad) ^ (l15 & 7)) * 8));
#pragma unroll
      for (int j = 0; j < 4; j++)
        bf[j] = *(const bf16x8*)(Bs + (wn + j * 16 + l15) * 64 + (((s * 4 + quad) ^ (l15 & 7)) * 8));
#pragma unroll
      for (int i = 0; i < 4; i++)
#pragma unroll
        for (int j = 0; j < 4; j++)
          acc[i][j] = __builtin_amdgcn_mfma_f32_16x16x32_bf16(af[i], bf[j], acc[i][j], 0, 0, 0);
    }
  }
  int hs = (n0 + wn) >> 6;
  if (hs < 20) {
    bool isq = hs < 16;
    float postscale = isq ? 0.216404256f : 1.2f;
#pragma unroll
    for (int i = 0; i < 4; i++) {
#pragma unroll
      for (int r = 0; r < 4; r++) {
        int row = m0 + wm + i * 16 + quad * 4 + r;
        int s = row & 2047, b = row >> 11;
        float c0 = cosb[s * 32 + l15],      s0 = sinb[s * 32 + l15];
        float c1 = cosb[s * 32 + 16 + l15], s1 = sinb[s * 32 + 16 + l15];
        float v0 = acc[i][0][r], v1 = acc[i][1][r], v2 = acc[i][2][r], v3 = acc[i][3][r];
        float n0v = fmaf(v0, c0,  v2 * s0);
        float n1v = fmaf(v1, c1,  v3 * s1);
        float n2v = fmaf(v2, c0, -v0 * s0);
        float n3v = fmaf(v3, c1, -v1 * s1);
        float ss = (n0v * n0v + n1v * n1v) + (n2v * n2v + n3v * n3v);
        ss += __shfl_xor(ss, 1, 64); ss += __shfl_xor(ss, 2, 64);
        ss += __shfl_xor(ss, 4, 64); ss += __shfl_xor(ss, 8, 64);
        float sc = rsqrtf(ss * (1.0f / 64.0f) + 1.1920929e-07f) * postscale;
        unsigned short* dp = isq ? Q + ((size_t)(b * 16 + hs) * 2048 + s) * 64
                                 : Kd + ((size_t)(b * 4 + hs - 16) * 2048 + s) * 64;
        dp[l15]      = f2bf(n0v * sc);
        dp[16 + l15] = f2bf(n1v * sc);
        dp[32 + l15] = f2bf(n2v * sc);
        dp[48 + l15] = f2bf(n3v * sc);
      }
    }
  } else {
    int khl = wave & 1;
    int kh = hs - 20;
#pragma unroll
    for (int i = 0; i < 4; i++) {
#pragma unroll
      for (int r = 0; r < 4; r++) {
        int rl = wm + i * 16 + quad * 4 + r;
        int row = m0 + rl, s = row & 2047, b = row >> 11;
        float g = gLDS[khl * 128 + rl];
        const float* vep = ve + (size_t)row * 256 + kh * 64;
        unsigned short* vp = Vt + ((size_t)(b * 4 + kh) * 64) * 2048 + s;
#pragma unroll
        for (int j = 0; j < 4; j++) {
          float vv = fmaf(g, vep[j * 16 + l15], acc[i][j][r]);
          vp[(size_t)(j * 16 + l15) * 2048] = f2bf(vv);
        }
      }
    }
  }
}

// Causal flash attention, GQA 4:1, NO-MAX softmax (exp2-domain partials), split-K x4.
// 128-QUERY tiles: 4 waves x 32 q (two 16-q rows/wave) -> 32 MFMA per staged 64-key
// tile (2x the old ratio). Single-buffer K/V, gld16 + XOR swizzle (conflict-free),
// 25.6KB LDS -> 6 blocks/CU. Per-wave P region reused by both q-rows (same-wave DS
// ordering). Block = (pair, h, b*4+c); q-tiles {pair, 15-pair}.
__global__ __launch_bounds__(256) void flash_kernel(const unsigned short* __restrict__ Q,
                                                    const unsigned short* __restrict__ K,
                                                    const unsigned short* __restrict__ Vt,
                                                    unsigned short* __restrict__ accP,
                                                    float* __restrict__ lP) {
  __shared__ unsigned short Ks[64 * 64];         // [key][dim], chunk-swizzled
  __shared__ unsigned short Vs[64 * 64];         // [dim][key], chunk-swizzled
  __shared__ unsigned short Ps[4 * 16 * LROW];   // per-wave P [q16][key], padded
  int pair = blockIdx.x, h = blockIdx.y, bc = blockIdx.z;
  int b = bc >> 2, c = bc & 3;
  int hb = b * 16 + h;
  int kh = h >> 2;
  int tid = threadIdx.x, wave = tid >> 6, lane = tid & 63, l15 = lane & 15, quad = lane >> 4;
  int l7 = l15 & 7;
  const unsigned short* Kg = K + (size_t)(b * 4 + kh) * 2048 * 64;
  const unsigned short* Vg = Vt + (size_t)(b * 4 + kh) * 64 * 2048;
  unsigned short* Pw = Ps + wave * 16 * LROW;
  int srow = lane >> 3;                      // staging row within 8-group
  int scol = ((lane & 7) ^ srow) * 8;        // swizzled source chunk

#pragma unroll
  for (int half = 0; half < 2; half++) {
    int qt = (half == 0) ? pair : 15 - pair;       // 128-query tile index
    int ntiles = 2 * qt + 2;                       // 64-key tiles in causal range
    int c0t = (ntiles * c) >> 2;
    int c1t = (ntiles * (c + 1)) >> 2;
    int q0 = qt * 128;
    bf16x8 qf[2][2];
#pragma unroll
    for (int r = 0; r < 2; r++) {
      const unsigned short* Qp =
          Q + ((size_t)hb * 2048 + q0 + wave * 32 + r * 16 + l15) * 64;
      qf[r][0] = *(const bf16x8*)(Qp + quad * 8);
      qf[r][1] = *(const bf16x8*)(Qp + 32 + quad * 8);
    }
    f32x4 acc[2][4];
#pragma unroll
    for (int r = 0; r < 2; r++)
#pragma unroll
      for (int i = 0; i < 4; i++) acc[r][i] = (f32x4){0.f, 0.f, 0.f, 0.f};
    float l_lane[2] = {0.f, 0.f};

    for (int kt = c0t; kt < c1t; kt++) {
      int k0 = kt * 64;
      __syncthreads();  // protect prior tile's LDS reads
#pragma unroll
      for (int j = 0; j < 2; j++) {
        int row = wave * 16 + j * 8;
#if HAVE_GLD
        gld16(Kg + (size_t)(k0 + row + srow) * 64 + scol, Ks + row * 64 + lane * 8);
        gld16(Vg + (size_t)(row + srow) * 2048 + k0 + scol, Vs + row * 64 + lane * 8);
#else
        *(float4*)(Ks + row * 64 + lane * 8) = *(const float4*)(Kg + (size_t)(k0 + row + srow) * 64 + scol);
        *(float4*)(Vs + row * 64 + lane * 8) = *(const float4*)(Vg + (size_t)(row + srow) * 2048 + k0 + scol);
#endif
      }
      __syncthreads();  // drain staging

      bf16x8 kf[4][2];
#pragma unroll
      for (int mt = 0; mt < 4; mt++) {
        kf[mt][0] = *(const bf16x8*)(Ks + (mt * 16 + l15) * 64 + ((quad ^ l7) * 8));
        kf[mt][1] = *(const bf16x8*)(Ks + (mt * 16 + l15) * 64 + (((4 + quad) ^ l7) * 8));
      }
      bool diag = (kt >= 2 * qt);  // last two tiles overlap the diagonal
#pragma unroll
      for (int r = 0; r < 2; r++) {
        // S^T: sv[mt][rr] = S[q=l15(row r)][key=k0+mt*16+quad*4+rr]
        f32x4 sv[4];
#pragma unroll
        for (int mt = 0; mt < 4; mt++) {
          sv[mt] = (f32x4){0.f, 0.f, 0.f, 0.f};
          sv[mt] = __builtin_amdgcn_mfma_f32_16x16x32_bf16(kf[mt][0], qf[r][0], sv[mt], 0, 0, 0);
          sv[mt] = __builtin_amdgcn_mfma_f32_16x16x32_bf16(kf[mt][1], qf[r][1], sv[mt], 0, 0, 0);
        }
        if (diag) {
          int qg = q0 + wave * 32 + r * 16 + l15;
#pragma unroll
          for (int mt = 0; mt < 4; mt++) {
            int kg = k0 + mt * 16 + quad * 4;
#pragma unroll
            for (int rr = 0; rr < 4; rr++)
              if (kg + rr > qg) sv[mt][rr] = -1e30f;
          }
        }
#pragma unroll
        for (int mt = 0; mt < 4; mt++) {
          float p0 = __builtin_amdgcn_exp2f(sv[mt][0]);
          float p1 = __builtin_amdgcn_exp2f(sv[mt][1]);
          float p2 = __builtin_amdgcn_exp2f(sv[mt][2]);
          float p3 = __builtin_amdgcn_exp2f(sv[mt][3]);
          l_lane[r] += (p0 + p1) + (p2 + p3);
          unsigned int lo = __builtin_amdgcn_perm(__float_as_uint(p1), __float_as_uint(p0), 0x07060302u);
          unsigned int hi = __builtin_amdgcn_perm(__float_as_uint(p3), __float_as_uint(p2), 0x07060302u);
          *(uint2*)(Pw + l15 * LROW + mt * 16 + quad * 4) = make_uint2(lo, hi);
        }
        // PV: A = P rows (q=l15), B = V^T fragments. Same-wave DS ordering, no barrier;
        // row r+1 overwrites Pw only after row r's reads (program order per wave).
#pragma unroll
        for (int step = 0; step < 2; step++) {
          bf16x8 pa = *(const bf16x8*)(Pw + l15 * LROW + step * 32 + quad * 8);
#pragma unroll
          for (int nt = 0; nt < 4; nt++) {
            bf16x8 vb = *(const bf16x8*)(Vs + (nt * 16 + l15) * 64 + (((step * 4 + quad) ^ l7) * 8));
            acc[r][nt] = __builtin_amdgcn_mfma_f32_16x16x32_bf16(pa, vb, acc[r][nt], 0, 0, 0);
          }
        }
      }
    }
#pragma unroll
    for (int r = 0; r < 2; r++) {
      float l = l_lane[r];
      l += __shfl_xor(l, 16, 64);
      l += __shfl_xor(l, 32, 64);
      size_t slot = (size_t)(c * 32 + hb) * 2048 + q0 + wave * 32 + r * 16;
      if (lane < 16) lP[slot + l15] = l;
      unsigned short* aP = accP + slot * 64;
#pragma unroll
      for (int rr = 0; rr < 4; rr++)
#pragma unroll
        for (int nt = 0; nt < 4; nt++)
          aP[(size_t)(quad * 4 + rr) * 64 + nt * 16 + l15] = f2bf(acc[r][nt][rr]);
    }
  }
}

// merge NSPLIT split-K partials: Y = (Σa_c)/(Σl_c), bf16 out. 4 d-elems/thread.
__global__ __launch_bounds__(256) void merge_kernel(const unsigned short* __restrict__ accP,
                                                    const float* __restrict__ lP,
                                                    unsigned short* __restrict__ Y) {
  int t = blockIdx.x * 256 + threadIdx.x;
  int d4 = (t & 15) * 4;
  int q  = (t >> 4) & 2047;
  int hb = t >> 15;
  const size_t CSTR = (size_t)32 * 2048 * 64;
  size_t pi = ((size_t)hb * 2048 + q) * 64 + d4;
  float y0 = 0.f, y1 = 0.f, y2 = 0.f, y3 = 0.f, l = 0.f;
#pragma unroll
  for (int c = 0; c < NSPLIT; c++) {
    ushort4 a = *(const ushort4*)(accP + pi + c * CSTR);
    y0 += bf2f(a.x); y1 += bf2f(a.y); y2 += bf2f(a.z); y3 += bf2f(a.w);
    l += lP[c * 65536 + hb * 2048 + q];
  }
  float inv = 1.f / l;
  ushort4 o;
  o.x = f2bf(y0 * inv); o.y = f2bf(y1 * inv); o.z = f2bf(y2 * inv); o.w = f2bf(y3 * inv);
  int b = hb >> 4, hh = hb & 15;
  *(ushort4*)(Y + ((size_t)(b * 2048 + q) * 1024) + hh * 64 + d4) = o;
}

extern "C" void kernel_launch(void* const* d_in, const int* in_sizes, int n_in,
                              void* d_out, int out_size, void* d_ws, size_t ws_size,
                              hipStream_t stream) {
  const float* x     = (const float*)d_in[0];
  const float* ve    = (const float*)d_in[1];
  const float* cosb  = (const float*)d_in[2];
  const float* sinb  = (const float*)d_in[3];
  // d_in[4] attn_mask: causal, hard-coded
  const float* Wq    = (const float*)d_in[5];
  const float* Wk    = (const float*)d_in[6];
  const float* Wv    = (const float*)d_in[7];
  const float* Wproj = (const float*)d_in[8];
  const float* Wgate = (const float*)d_in[9];
  float* out = (float*)d_out;
  char* ws = (char*)d_ws;

  size_t o = 0;
  unsigned short* xb   = (unsigned short*)(ws + o); o += (size_t)4096 * 1024 * 2;
  unsigned short* wqkv = (unsigned short*)(ws + o); o += (size_t)1536 * 1024 * 2;
  unsigned short* wpj  = (unsigned short*)(ws + o); o += (size_t)1024 * 1024 * 2;
  unsigned short* Qb   = (unsigned short*)(ws + o); o += (size_t)2 * 16 * 2048 * 64 * 2;
  unsigned short* Kb   = (unsigned short*)(ws + o); o += (size_t)2 * 4 * 2048 * 64 * 2;
  unsigned short* Vb   = (unsigned short*)(ws + o); o += (size_t)2 * 4 * 2048 * 64 * 2; // [b][kh][d][s]
  unsigned short* Yb   = (unsigned short*)(ws + o); o += (size_t)4096 * 1024 * 2;
  unsigned short* accP = (unsigned short*)(ws + o); o += (size_t)NSPLIT * 32 * 2048 * 64 * 2;
  float*          lP   = (float*)(ws + o);          o += (size_t)NSPLIT * 32 * 2048 * 4;

  hipLaunchKernelGGL(cvt_all_kernel, dim3(6656), dim3(256), 0, stream,
                     x, Wq, Wk, Wv, Wproj, xb, wqkv, wpj);
  hipLaunchKernelGGL(gemm_qkv_kernel, dim3(12, 32), dim3(256), 0, stream,
                     xb, wqkv, ve, cosb, sinb, Wgate, Qb, Kb, Vb);
  hipLaunchKernelGGL(flash_kernel, dim3(8, 16, 2 * NSPLIT), dim3(256), 0, stream,
                     Qb, Kb, Vb, accP, lP);
  hipLaunchKernelGGL(merge_kernel, dim3(4096), dim3(256), 0, stream, accP, lP, Yb);
  hipLaunchKernelGGL(gemm128_kernel, dim3(8, 32), dim3(256), 0, stream, Yb, wpj, out, 4096, 1024, 1024);
}

// Round 10
// 192.358 us; speedup vs baseline: 1.1654x; 1.0726x over previous
//
#include <hip/hip_runtime.h>
#include <hip/hip_bf16.h>
#include <math.h>

typedef short bf16x8 __attribute__((ext_vector_type(8)));
typedef float f32x4 __attribute__((ext_vector_type(4)));

#define LROW 72   // padded LDS row for P (bf16 elems): 2-way alias, free
#define NSPLIT 2  // flash split-K chunks

__device__ __forceinline__ unsigned short f2bf(float f) {
  union { float f; unsigned int u; } v; v.f = f;
  unsigned int u = v.u;
  unsigned int r = (u + 0x7fffu + ((u >> 16) & 1u)) >> 16;
  return (unsigned short)r;
}
__device__ __forceinline__ float bf2f(unsigned short u) {
  return __uint_as_float((unsigned)u << 16);
}

#if __has_builtin(__builtin_amdgcn_global_load_lds)
#define HAVE_GLD 1
__device__ __forceinline__ void gld16(const void* g, void* l) {
  __builtin_amdgcn_global_load_lds(
      (const __attribute__((address_space(1))) unsigned int*)g,
      (__attribute__((address_space(3))) unsigned int*)l, 16, 0, 0);
}
#else
#define HAVE_GLD 0
#endif

// All fp32->bf16 converts: x (4096 blk), Wq(1024), Wk(256), Wv(256), Wproj(1024)
__global__ __launch_bounds__(256) void cvt_all_kernel(const float* __restrict__ x,
                                                      const float* __restrict__ Wq,
                                                      const float* __restrict__ Wk,
                                                      const float* __restrict__ Wv,
                                                      const float* __restrict__ Wproj,
                                                      unsigned short* __restrict__ xb,
                                                      unsigned short* __restrict__ wqkv,
                                                      unsigned short* __restrict__ wpj) {
  int blk = blockIdx.x;
  const float* src;
  unsigned short* dst;
  if (blk < 4096)      { src = x + (size_t)blk * 1024;            dst = xb + (size_t)blk * 1024; }
  else if (blk < 5120) { src = Wq + (size_t)(blk - 4096) * 1024;  dst = wqkv + (size_t)(blk - 4096) * 1024; }
  else if (blk < 5376) { src = Wk + (size_t)(blk - 5120) * 1024;  dst = wqkv + (size_t)(blk - 4096) * 1024; }
  else if (blk < 5632) { src = Wv + (size_t)(blk - 5376) * 1024;  dst = wqkv + (size_t)(blk - 4096) * 1024; }
  else                 { src = Wproj + (size_t)(blk - 5632) * 1024; dst = wpj + (size_t)(blk - 5632) * 1024; }
  int i = threadIdx.x;
  float4 v = ((const float4*)src)[i];
  ushort4 o;
  o.x = f2bf(v.x); o.y = f2bf(v.y); o.z = f2bf(v.z); o.w = f2bf(v.w);
  ((ushort4*)dst)[i] = o;
}

// Plain GEMM C[M][N] = A[M][K] x B[N][K]^T; 128x128 tile, BK=64, gld16 staging, XOR swizzle.
__global__ __launch_bounds__(256) void gemm128_kernel(const unsigned short* __restrict__ A,
                                                      const unsigned short* __restrict__ B,
                                                      float* __restrict__ C, int M, int N, int K) {
  __shared__ unsigned short As[128 * 64];
  __shared__ unsigned short Bs[128 * 64];
  int tid = threadIdx.x;
  int wave = tid >> 6, lane = tid & 63, l15 = lane & 15, quad = lane >> 4;
  int wm = (wave >> 1) * 64, wn = (wave & 1) * 64;
  int n0 = blockIdx.x * 128, m0 = blockIdx.y * 128;
  f32x4 acc[4][4];
#pragma unroll
  for (int i = 0; i < 4; i++)
#pragma unroll
    for (int j = 0; j < 4; j++) acc[i][j] = (f32x4){0.f, 0.f, 0.f, 0.f};
  int srow = lane >> 3;
  int scol = ((lane & 7) ^ srow) * 8;
  for (int k0 = 0; k0 < K; k0 += 64) {
    __syncthreads();
#if HAVE_GLD
#pragma unroll
    for (int i = 0; i < 4; i++) {
      int row = wave * 32 + i * 8;
      gld16(A + (size_t)(m0 + row + srow) * K + k0 + scol, As + row * 64 + lane * 8);
      gld16(B + (size_t)(n0 + row + srow) * K + k0 + scol, Bs + row * 64 + lane * 8);
    }
#else
#pragma unroll
    for (int i = 0; i < 4; i++) {
      int row = wave * 32 + i * 8;
      *(float4*)(As + row * 64 + lane * 8) = *(const float4*)(A + (size_t)(m0 + row + srow) * K + k0 + scol);
      *(float4*)(Bs + row * 64 + lane * 8) = *(const float4*)(B + (size_t)(n0 + row + srow) * K + k0 + scol);
    }
#endif
    __syncthreads();
#pragma unroll
    for (int s = 0; s < 2; s++) {
      bf16x8 af[4], bf[4];
#pragma unroll
      for (int i = 0; i < 4; i++)
        af[i] = *(const bf16x8*)(As + (wm + i * 16 + l15) * 64 + (((s * 4 + quad) ^ (l15 & 7)) * 8));
#pragma unroll
      for (int j = 0; j < 4; j++)
        bf[j] = *(const bf16x8*)(Bs + (wn + j * 16 + l15) * 64 + (((s * 4 + quad) ^ (l15 & 7)) * 8));
#pragma unroll
      for (int i = 0; i < 4; i++)
#pragma unroll
        for (int j = 0; j < 4; j++)
          acc[i][j] = __builtin_amdgcn_mfma_f32_16x16x32_bf16(af[i], bf[j], acc[i][j], 0, 0, 0);
    }
  }
#pragma unroll
  for (int i = 0; i < 4; i++)
#pragma unroll
    for (int j = 0; j < 4; j++)
#pragma unroll
      for (int r = 0; r < 4; r++)
        C[(size_t)(m0 + wm + i * 16 + quad * 4 + r) * N + n0 + wn + j * 16 + l15] = acc[i][j][r];
}

// Fused qkv GEMM (M=4096,N=1536,K=1024) + rope/rms/gate epilogue.
// Wave's 64 cols = head-slot hs: 0-15 Q, 16-19 K, 20-23 V.
// Q scaled 1.2*0.125*log2(e), K 1.2. V += gate*ve, written [b][kh][d][s].
__global__ __launch_bounds__(256) void gemm_qkv_kernel(const unsigned short* __restrict__ A,
                                                       const unsigned short* __restrict__ B,
                                                       const float* __restrict__ ve,
                                                       const float* __restrict__ cosb,
                                                       const float* __restrict__ sinb,
                                                       const float* __restrict__ wgate,
                                                       unsigned short* __restrict__ Q,
                                                       unsigned short* __restrict__ Kd,
                                                       unsigned short* __restrict__ Vt) {
  __shared__ unsigned short As[128 * 64];
  __shared__ unsigned short Bs[128 * 64];
  __shared__ float gLDS[256];
  const int K = 1024;
  int tid = threadIdx.x;
  int wave = tid >> 6, lane = tid & 63, l15 = lane & 15, quad = lane >> 4;
  int wm = (wave >> 1) * 64, wn = (wave & 1) * 64;
  int n0 = blockIdx.x * 128, m0 = blockIdx.y * 128;
  if (n0 >= 1280) {
    int rl = tid & 127, khl2 = tid >> 7;
    int kh = ((n0 >> 6) - 20) + khl2;
    float dot = 0.f;
#pragma unroll
    for (int jj = 0; jj < 12; jj++)
      dot += bf2f(A[(size_t)(m0 + rl) * 1024 + jj]) * wgate[kh * 12 + jj];
    gLDS[khl2 * 128 + rl] = 3.0f / (1.0f + __expf(-dot));
  }
  f32x4 acc[4][4];
#pragma unroll
  for (int i = 0; i < 4; i++)
#pragma unroll
    for (int j = 0; j < 4; j++) acc[i][j] = (f32x4){0.f, 0.f, 0.f, 0.f};
  int srow = lane >> 3;
  int scol = ((lane & 7) ^ srow) * 8;
  for (int k0 = 0; k0 < K; k0 += 64) {
    __syncthreads();
#if HAVE_GLD
#pragma unroll
    for (int i = 0; i < 4; i++) {
      int row = wave * 32 + i * 8;
      gld16(A + (size_t)(m0 + row + srow) * K + k0 + scol, As + row * 64 + lane * 8);
      gld16(B + (size_t)(n0 + row + srow) * K + k0 + scol, Bs + row * 64 + lane * 8);
    }
#else
#pragma unroll
    for (int i = 0; i < 4; i++) {
      int row = wave * 32 + i * 8;
      *(float4*)(As + row * 64 + lane * 8) = *(const float4*)(A + (size_t)(m0 + row + srow) * K + k0 + scol);
      *(float4*)(Bs + row * 64 + lane * 8) = *(const float4*)(B + (size_t)(n0 + row + srow) * K + k0 + scol);
    }
#endif
    __syncthreads();
#pragma unroll
    for (int s = 0; s < 2; s++) {
      bf16x8 af[4], bf[4];
#pragma unroll
      for (int i = 0; i < 4; i++)
        af[i] = *(const bf16x8*)(As + (wm + i * 16 + l15) * 64 + (((s * 4 + quad) ^ (l15 & 7)) * 8));
#pragma unroll
      for (int j = 0; j < 4; j++)
        bf[j] = *(const bf16x8*)(Bs + (wn + j * 16 + l15) * 64 + (((s * 4 + quad) ^ (l15 & 7)) * 8));
#pragma unroll
      for (int i = 0; i < 4; i++)
#pragma unroll
        for (int j = 0; j < 4; j++)
          acc[i][j] = __builtin_amdgcn_mfma_f32_16x16x32_bf16(af[i], bf[j], acc[i][j], 0, 0, 0);
    }
  }
  int hs = (n0 + wn) >> 6;
  if (hs < 20) {
    bool isq = hs < 16;
    float postscale = isq ? 0.216404256f : 1.2f;
#pragma unroll
    for (int i = 0; i < 4; i++) {
#pragma unroll
      for (int r = 0; r < 4; r++) {
        int row = m0 + wm + i * 16 + quad * 4 + r;
        int s = row & 2047, b = row >> 11;
        float c0 = cosb[s * 32 + l15],      s0 = sinb[s * 32 + l15];
        float c1 = cosb[s * 32 + 16 + l15], s1 = sinb[s * 32 + 16 + l15];
        float v0 = acc[i][0][r], v1 = acc[i][1][r], v2 = acc[i][2][r], v3 = acc[i][3][r];
        float n0v = fmaf(v0, c0,  v2 * s0);
        float n1v = fmaf(v1, c1,  v3 * s1);
        float n2v = fmaf(v2, c0, -v0 * s0);
        float n3v = fmaf(v3, c1, -v1 * s1);
        float ss = (n0v * n0v + n1v * n1v) + (n2v * n2v + n3v * n3v);
        ss += __shfl_xor(ss, 1, 64); ss += __shfl_xor(ss, 2, 64);
        ss += __shfl_xor(ss, 4, 64); ss += __shfl_xor(ss, 8, 64);
        float sc = rsqrtf(ss * (1.0f / 64.0f) + 1.1920929e-07f) * postscale;
        unsigned short* dp = isq ? Q + ((size_t)(b * 16 + hs) * 2048 + s) * 64
                                 : Kd + ((size_t)(b * 4 + hs - 16) * 2048 + s) * 64;
        dp[l15]      = f2bf(n0v * sc);
        dp[16 + l15] = f2bf(n1v * sc);
        dp[32 + l15] = f2bf(n2v * sc);
        dp[48 + l15] = f2bf(n3v * sc);
      }
    }
  } else {
    int khl = wave & 1;
    int kh = hs - 20;
#pragma unroll
    for (int i = 0; i < 4; i++) {
#pragma unroll
      for (int r = 0; r < 4; r++) {
        int rl = wm + i * 16 + quad * 4 + r;
        int row = m0 + rl, s = row & 2047, b = row >> 11;
        float g = gLDS[khl * 128 + rl];
        const float* vep = ve + (size_t)row * 256 + kh * 64;
        unsigned short* vp = Vt + ((size_t)(b * 4 + kh) * 64) * 2048 + s;
#pragma unroll
        for (int j = 0; j < 4; j++) {
          float vv = fmaf(g, vep[j * 16 + l15], acc[i][j][r]);
          vp[(size_t)(j * 16 + l15) * 2048] = f2bf(vv);
        }
      }
    }
  }
}

// Causal flash attention, GQA 4:1, NO-MAX softmax (exp2-domain partials), split-K x2,
// per-head blocks. r4 structure (reg-prefetch dbuf via VGPRs, float4 staging, low VGPR)
// with UNPADDED XOR-SWIZZLED K/V LDS: 25.2KB -> 6 blocks/CU. Block = (pair, h, b*2+c).
__global__ __launch_bounds__(256) void flash_kernel(const unsigned short* __restrict__ Q,
                                                    const unsigned short* __restrict__ K,
                                                    const unsigned short* __restrict__ Vt,
                                                    unsigned short* __restrict__ accP,
                                                    float* __restrict__ lP) {
  __shared__ unsigned short Ks[64 * 64];         // [key][dim], chunk-swizzled
  __shared__ unsigned short Vs[64 * 64];         // [dim][key], chunk-swizzled
  __shared__ unsigned short Ps[4 * 16 * LROW];   // per-wave P [q][key], padded
  int pair = blockIdx.x, h = blockIdx.y, bc = blockIdx.z;
  int b = bc >> 1, c = bc & 1;
  int hb = b * 16 + h;
  int kh = h >> 2;
  int tid = threadIdx.x, wave = tid >> 6, lane = tid & 63, l15 = lane & 15, quad = lane >> 4;
  int l7 = l15 & 7;
  const unsigned short* Kg = K + (size_t)(b * 4 + kh) * 2048 * 64;
  const unsigned short* Vg = Vt + (size_t)(b * 4 + kh) * 64 * 2048;
  unsigned short* Pw = Ps + wave * 16 * LROW;
  int row0 = tid >> 3, col8 = (tid & 7) * 8;            // staging: rows {row0, row0+32}
  int dchunk = (((tid & 7) ^ (row0 & 7)) * 8);          // swizzled dest chunk (both rows)

#pragma unroll
  for (int half = 0; half < 2; half++) {
    int qt = (half == 0) ? pair : 31 - pair;
    int c0t = (c == 0) ? 0 : (qt + 2) >> 1;       // chunk key-tile range [c0t, c1t)
    int c1t = (c == 0) ? ((qt + 2) >> 1) : qt + 1;
    int q0 = qt * 64;
    const unsigned short* Qp = Q + (((size_t)hb * 2048) + q0 + wave * 16 + l15) * 64;
    bf16x8 qf0 = *(const bf16x8*)(Qp + quad * 8);
    bf16x8 qf1 = *(const bf16x8*)(Qp + 32 + quad * 8);
    f32x4 acc[4];
#pragma unroll
    for (int i = 0; i < 4; i++) acc[i] = (f32x4){0.f, 0.f, 0.f, 0.f};
    float l_lane = 0.f;

    if (c1t > c0t) {
      // prefetch first k-tile of chunk into regs
      int kf = c0t * 64;
      float4 pk0 = *(const float4*)(Kg + (size_t)(kf + row0) * 64 + col8);
      float4 pk1 = *(const float4*)(Kg + (size_t)(kf + row0 + 32) * 64 + col8);
      float4 pv0 = *(const float4*)(Vg + (size_t)row0 * 2048 + kf + col8);
      float4 pv1 = *(const float4*)(Vg + (size_t)(row0 + 32) * 2048 + kf + col8);

      for (int kt = c0t; kt < c1t; kt++) {
        int k0 = kt * 64;
        __syncthreads();  // prior consumers of Ks/Vs done
        *(float4*)(Ks + row0 * 64 + dchunk) = pk0;
        *(float4*)(Ks + (row0 + 32) * 64 + dchunk) = pk1;
        *(float4*)(Vs + row0 * 64 + dchunk) = pv0;
        *(float4*)(Vs + (row0 + 32) * 64 + dchunk) = pv1;
        if (kt + 1 < c1t) {  // prefetch next tile while computing this one
          int kn = k0 + 64;
          pk0 = *(const float4*)(Kg + (size_t)(kn + row0) * 64 + col8);
          pk1 = *(const float4*)(Kg + (size_t)(kn + row0 + 32) * 64 + col8);
          pv0 = *(const float4*)(Vg + (size_t)row0 * 2048 + kn + col8);
          pv1 = *(const float4*)(Vg + (size_t)(row0 + 32) * 2048 + kn + col8);
        }
        __syncthreads();

        // S^T: sv[mt][r] = S[q=l15][key=k0+mt*16+quad*4+r]
        f32x4 sv[4];
#pragma unroll
        for (int mt = 0; mt < 4; mt++) {
          sv[mt] = (f32x4){0.f, 0.f, 0.f, 0.f};
          bf16x8 k0f = *(const bf16x8*)(Ks + (mt * 16 + l15) * 64 + ((quad ^ l7) * 8));
          sv[mt] = __builtin_amdgcn_mfma_f32_16x16x32_bf16(k0f, qf0, sv[mt], 0, 0, 0);
          bf16x8 k1f = *(const bf16x8*)(Ks + (mt * 16 + l15) * 64 + (((4 + quad) ^ l7) * 8));
          sv[mt] = __builtin_amdgcn_mfma_f32_16x16x32_bf16(k1f, qf1, sv[mt], 0, 0, 0);
        }
        if (kt == qt) {  // diagonal: causal mask (key > q)
          int qg = q0 + wave * 16 + l15;
#pragma unroll
          for (int mt = 0; mt < 4; mt++) {
            int kg = k0 + mt * 16 + quad * 4;
#pragma unroll
            for (int r = 0; r < 4; r++)
              if (kg + r > qg) sv[mt][r] = -1e30f;
          }
        }
#pragma unroll
        for (int mt = 0; mt < 4; mt++) {
          float p0 = __builtin_amdgcn_exp2f(sv[mt][0]);
          float p1 = __builtin_amdgcn_exp2f(sv[mt][1]);
          float p2 = __builtin_amdgcn_exp2f(sv[mt][2]);
          float p3 = __builtin_amdgcn_exp2f(sv[mt][3]);
          l_lane += (p0 + p1) + (p2 + p3);
          unsigned int lo = __builtin_amdgcn_perm(__float_as_uint(p1), __float_as_uint(p0), 0x07060302u);
          unsigned int hi = __builtin_amdgcn_perm(__float_as_uint(p3), __float_as_uint(p2), 0x07060302u);
          *(uint2*)(Pw + l15 * LROW + mt * 16 + quad * 4) = make_uint2(lo, hi);
        }
        // PV: A = P rows (q=l15), B = V^T fragments. Same-wave DS ordering, no barrier.
#pragma unroll
        for (int step = 0; step < 2; step++) {
          bf16x8 pa = *(const bf16x8*)(Pw + l15 * LROW + step * 32 + quad * 8);
#pragma unroll
          for (int nt = 0; nt < 4; nt++) {
            bf16x8 vb = *(const bf16x8*)(Vs + (nt * 16 + l15) * 64 + (((step * 4 + quad) ^ l7) * 8));
            acc[nt] = __builtin_amdgcn_mfma_f32_16x16x32_bf16(pa, vb, acc[nt], 0, 0, 0);
          }
        }
      }
    }
    l_lane += __shfl_xor(l_lane, 16, 64);
    l_lane += __shfl_xor(l_lane, 32, 64);

    size_t slot = (size_t)(c * 32 + hb) * 2048 + q0 + wave * 16;
    if (lane < 16) lP[slot + l15] = l_lane;
    unsigned short* aP = accP + slot * 64;
#pragma unroll
    for (int r = 0; r < 4; r++)
#pragma unroll
      for (int nt = 0; nt < 4; nt++)
        aP[(size_t)(quad * 4 + r) * 64 + nt * 16 + l15] = f2bf(acc[nt][r]);
  }
}

// merge NSPLIT split-K partials: Y = (Σa_c)/(Σl_c), bf16 out. 4 d-elems/thread.
__global__ __launch_bounds__(256) void merge_kernel(const unsigned short* __restrict__ accP,
                                                    const float* __restrict__ lP,
                                                    unsigned short* __restrict__ Y) {
  int t = blockIdx.x * 256 + threadIdx.x;
  int d4 = (t & 15) * 4;
  int q  = (t >> 4) & 2047;
  int hb = t >> 15;
  const size_t CSTR = (size_t)32 * 2048 * 64;
  size_t pi = ((size_t)hb * 2048 + q) * 64 + d4;
  float y0 = 0.f, y1 = 0.f, y2 = 0.f, y3 = 0.f, l = 0.f;
#pragma unroll
  for (int c = 0; c < NSPLIT; c++) {
    ushort4 a = *(const ushort4*)(accP + pi + c * CSTR);
    y0 += bf2f(a.x); y1 += bf2f(a.y); y2 += bf2f(a.z); y3 += bf2f(a.w);
    l += lP[c * 65536 + hb * 2048 + q];
  }
  float inv = 1.f / l;
  ushort4 o;
  o.x = f2bf(y0 * inv); o.y = f2bf(y1 * inv); o.z = f2bf(y2 * inv); o.w = f2bf(y3 * inv);
  int b = hb >> 4, hh = hb & 15;
  *(ushort4*)(Y + ((size_t)(b * 2048 + q) * 1024) + hh * 64 + d4) = o;
}

extern "C" void kernel_launch(void* const* d_in, const int* in_sizes, int n_in,
                              void* d_out, int out_size, void* d_ws, size_t ws_size,
                              hipStream_t stream) {
  const float* x     = (const float*)d_in[0];
  const float* ve    = (const float*)d_in[1];
  const float* cosb  = (const float*)d_in[2];
  const float* sinb  = (const float*)d_in[3];
  // d_in[4] attn_mask: causal, hard-coded
  const float* Wq    = (const float*)d_in[5];
  const float* Wk    = (const float*)d_in[6];
  const float* Wv    = (const float*)d_in[7];
  const float* Wproj = (const float*)d_in[8];
  const float* Wgate = (const float*)d_in[9];
  float* out = (float*)d_out;
  char* ws = (char*)d_ws;

  size_t o = 0;
  unsigned short* xb   = (unsigned short*)(ws + o); o += (size_t)4096 * 1024 * 2;
  unsigned short* wqkv = (unsigned short*)(ws + o); o += (size_t)1536 * 1024 * 2;
  unsigned short* wpj  = (unsigned short*)(ws + o); o += (size_t)1024 * 1024 * 2;
  unsigned short* Qb   = (unsigned short*)(ws + o); o += (size_t)2 * 16 * 2048 * 64 * 2;
  unsigned short* Kb   = (unsigned short*)(ws + o); o += (size_t)2 * 4 * 2048 * 64 * 2;
  unsigned short* Vb   = (unsigned short*)(ws + o); o += (size_t)2 * 4 * 2048 * 64 * 2; // [b][kh][d][s]
  unsigned short* Yb   = (unsigned short*)(ws + o); o += (size_t)4096 * 1024 * 2;
  unsigned short* accP = (unsigned short*)(ws + o); o += (size_t)NSPLIT * 32 * 2048 * 64 * 2;
  float*          lP   = (float*)(ws + o);          o += (size_t)NSPLIT * 32 * 2048 * 4;

  hipLaunchKernelGGL(cvt_all_kernel, dim3(6656), dim3(256), 0, stream,
                     x, Wq, Wk, Wv, Wproj, xb, wqkv, wpj);
  hipLaunchKernelGGL(gemm_qkv_kernel, dim3(12, 32), dim3(256), 0, stream,
                     xb, wqkv, ve, cosb, sinb, Wgate, Qb, Kb, Vb);
  hipLaunchKernelGGL(flash_kernel, dim3(16, 16, 2 * NSPLIT), dim3(256), 0, stream,
                     Qb, Kb, Vb, accP, lP);
  hipLaunchKernelGGL(merge_kernel, dim3(4096), dim3(256), 0, stream, accP, lP, Yb);
  hipLaunchKernelGGL(gemm128_kernel, dim3(8, 32), dim3(256), 0, stream, Yb, wpj, out, 4096, 1024, 1024);
}

// Round 11
// 183.840 us; speedup vs baseline: 1.2194x; 1.0463x over previous
//
#include <hip/hip_runtime.h>
#include <hip/hip_bf16.h>
#include <math.h>

typedef short bf16x8 __attribute__((ext_vector_type(8)));
typedef float f32x4 __attribute__((ext_vector_type(4)));

#define LROW 72   // padded LDS row for P (bf16 elems): 2-way alias, free
#define NSPLIT 3  // flash split-K chunks

__device__ __forceinline__ unsigned short f2bf(float f) {
  union { float f; unsigned int u; } v; v.f = f;
  unsigned int u = v.u;
  unsigned int r = (u + 0x7fffu + ((u >> 16) & 1u)) >> 16;
  return (unsigned short)r;
}
__device__ __forceinline__ float bf2f(unsigned short u) {
  return __uint_as_float((unsigned)u << 16);
}

#if __has_builtin(__builtin_amdgcn_global_load_lds)
#define HAVE_GLD 1
__device__ __forceinline__ void gld16(const void* g, void* l) {
  __builtin_amdgcn_global_load_lds(
      (const __attribute__((address_space(1))) unsigned int*)g,
      (__attribute__((address_space(3))) unsigned int*)l, 16, 0, 0);
}
#else
#define HAVE_GLD 0
#endif

// All fp32->bf16 converts: x (4096 blk), Wq(1024), Wk(256), Wv(256), Wproj(1024)
__global__ __launch_bounds__(256) void cvt_all_kernel(const float* __restrict__ x,
                                                      const float* __restrict__ Wq,
                                                      const float* __restrict__ Wk,
                                                      const float* __restrict__ Wv,
                                                      const float* __restrict__ Wproj,
                                                      unsigned short* __restrict__ xb,
                                                      unsigned short* __restrict__ wqkv,
                                                      unsigned short* __restrict__ wpj) {
  int blk = blockIdx.x;
  const float* src;
  unsigned short* dst;
  if (blk < 4096)      { src = x + (size_t)blk * 1024;            dst = xb + (size_t)blk * 1024; }
  else if (blk < 5120) { src = Wq + (size_t)(blk - 4096) * 1024;  dst = wqkv + (size_t)(blk - 4096) * 1024; }
  else if (blk < 5376) { src = Wk + (size_t)(blk - 5120) * 1024;  dst = wqkv + (size_t)(blk - 4096) * 1024; }
  else if (blk < 5632) { src = Wv + (size_t)(blk - 5376) * 1024;  dst = wqkv + (size_t)(blk - 4096) * 1024; }
  else                 { src = Wproj + (size_t)(blk - 5632) * 1024; dst = wpj + (size_t)(blk - 5632) * 1024; }
  int i = threadIdx.x;
  float4 v = ((const float4*)src)[i];
  ushort4 o;
  o.x = f2bf(v.x); o.y = f2bf(v.y); o.z = f2bf(v.z); o.w = f2bf(v.w);
  ((ushort4*)dst)[i] = o;
}

// Fused qkv GEMM (M=4096,N=1536,K=1024) + rope/rms/gate epilogue. 64x128 TILE,
// grid (12,64) = 768 blocks (3/CU). Waves 2x2: wave = 32 rows x 64 cols (FULL head,
// epilogue stays in-wave). Q scaled 1.2*0.125*log2(e), K 1.2. V += gate*ve -> [b][kh][d][s].
__global__ __launch_bounds__(256) void gemm_qkv_kernel(const unsigned short* __restrict__ A,
                                                       const unsigned short* __restrict__ B,
                                                       const float* __restrict__ ve,
                                                       const float* __restrict__ cosb,
                                                       const float* __restrict__ sinb,
                                                       const float* __restrict__ wgate,
                                                       unsigned short* __restrict__ Q,
                                                       unsigned short* __restrict__ Kd,
                                                       unsigned short* __restrict__ Vt) {
  __shared__ unsigned short As[64 * 64];
  __shared__ unsigned short Bs[128 * 64];
  __shared__ float gLDS[128];
  const int K = 1024;
  int tid = threadIdx.x;
  int wave = tid >> 6, lane = tid & 63, l15 = lane & 15, quad = lane >> 4;
  int wm = (wave >> 1) * 32, wn = (wave & 1) * 64;
  int n0 = blockIdx.x * 128, m0 = blockIdx.y * 64;
  if (n0 >= 1280 && tid < 128) {
    int rl = tid & 63, khl = tid >> 6;
    int kh = ((n0 >> 6) - 20) + khl;
    float dot = 0.f;
#pragma unroll
    for (int jj = 0; jj < 12; jj++)
      dot += bf2f(A[(size_t)(m0 + rl) * 1024 + jj]) * wgate[kh * 12 + jj];
    gLDS[khl * 64 + rl] = 3.0f / (1.0f + __expf(-dot));
  }
  f32x4 acc[2][4];
#pragma unroll
  for (int i = 0; i < 2; i++)
#pragma unroll
    for (int j = 0; j < 4; j++) acc[i][j] = (f32x4){0.f, 0.f, 0.f, 0.f};
  int srow = lane >> 3;
  int scol = ((lane & 7) ^ srow) * 8;
  for (int k0 = 0; k0 < K; k0 += 64) {
    __syncthreads();
#if HAVE_GLD
#pragma unroll
    for (int j = 0; j < 2; j++) {
      int row = wave * 16 + j * 8;
      gld16(A + (size_t)(m0 + row + srow) * K + k0 + scol, As + row * 64 + lane * 8);
    }
#pragma unroll
    for (int j = 0; j < 4; j++) {
      int row = wave * 32 + j * 8;
      gld16(B + (size_t)(n0 + row + srow) * K + k0 + scol, Bs + row * 64 + lane * 8);
    }
#else
#pragma unroll
    for (int j = 0; j < 2; j++) {
      int row = wave * 16 + j * 8;
      *(float4*)(As + row * 64 + lane * 8) = *(const float4*)(A + (size_t)(m0 + row + srow) * K + k0 + scol);
    }
#pragma unroll
    for (int j = 0; j < 4; j++) {
      int row = wave * 32 + j * 8;
      *(float4*)(Bs + row * 64 + lane * 8) = *(const float4*)(B + (size_t)(n0 + row + srow) * K + k0 + scol);
    }
#endif
    __syncthreads();
#pragma unroll
    for (int s = 0; s < 2; s++) {
      bf16x8 af[2], bf[4];
#pragma unroll
      for (int i = 0; i < 2; i++)
        af[i] = *(const bf16x8*)(As + (wm + i * 16 + l15) * 64 + (((s * 4 + quad) ^ (l15 & 7)) * 8));
#pragma unroll
      for (int j = 0; j < 4; j++)
        bf[j] = *(const bf16x8*)(Bs + (wn + j * 16 + l15) * 64 + (((s * 4 + quad) ^ (l15 & 7)) * 8));
#pragma unroll
      for (int i = 0; i < 2; i++)
#pragma unroll
        for (int j = 0; j < 4; j++)
          acc[i][j] = __builtin_amdgcn_mfma_f32_16x16x32_bf16(af[i], bf[j], acc[i][j], 0, 0, 0);
    }
  }
  int hs = (n0 + wn) >> 6;
  if (hs < 20) {
    bool isq = hs < 16;
    float postscale = isq ? 0.216404256f : 1.2f;
#pragma unroll
    for (int i = 0; i < 2; i++) {
#pragma unroll
      for (int r = 0; r < 4; r++) {
        int row = m0 + wm + i * 16 + quad * 4 + r;
        int s = row & 2047, b = row >> 11;
        float c0 = cosb[s * 32 + l15],      s0 = sinb[s * 32 + l15];
        float c1 = cosb[s * 32 + 16 + l15], s1 = sinb[s * 32 + 16 + l15];
        float v0 = acc[i][0][r], v1 = acc[i][1][r], v2 = acc[i][2][r], v3 = acc[i][3][r];
        float n0v = fmaf(v0, c0,  v2 * s0);
        float n1v = fmaf(v1, c1,  v3 * s1);
        float n2v = fmaf(v2, c0, -v0 * s0);
        float n3v = fmaf(v3, c1, -v1 * s1);
        float ss = (n0v * n0v + n1v * n1v) + (n2v * n2v + n3v * n3v);
        ss += __shfl_xor(ss, 1, 64); ss += __shfl_xor(ss, 2, 64);
        ss += __shfl_xor(ss, 4, 64); ss += __shfl_xor(ss, 8, 64);
        float sc = rsqrtf(ss * (1.0f / 64.0f) + 1.1920929e-07f) * postscale;
        unsigned short* dp = isq ? Q + ((size_t)(b * 16 + hs) * 2048 + s) * 64
                                 : Kd + ((size_t)(b * 4 + hs - 16) * 2048 + s) * 64;
        dp[l15]      = f2bf(n0v * sc);
        dp[16 + l15] = f2bf(n1v * sc);
        dp[32 + l15] = f2bf(n2v * sc);
        dp[48 + l15] = f2bf(n3v * sc);
      }
    }
  } else {
    int kh = hs - 20;
#pragma unroll
    for (int i = 0; i < 2; i++) {
#pragma unroll
      for (int r = 0; r < 4; r++) {
        int rl = wm + i * 16 + quad * 4 + r;
        int row = m0 + rl, s = row & 2047, b = row >> 11;
        float g = gLDS[(wave & 1) * 64 + rl];
        const float* vep = ve + (size_t)row * 256 + kh * 64;
        unsigned short* vp = Vt + ((size_t)(b * 4 + kh) * 64) * 2048 + s;
#pragma unroll
        for (int j = 0; j < 4; j++) {
          float vv = fmaf(g, vep[j * 16 + l15], acc[i][j][r]);
          vp[(size_t)(j * 16 + l15) * 2048] = f2bf(vv);
        }
      }
    }
  }
}

// Causal flash attention, GQA 4:1, NO-MAX softmax (exp2-domain partials), split-K x3,
// per-head blocks, unpadded XOR-swizzled K/V LDS (25.2KB -> 6 blocks/CU), reg-prefetch
// double-buffering. Block = (pair, h, b*3+c); 1536 blocks = 6/CU.
__global__ __launch_bounds__(256) void flash_kernel(const unsigned short* __restrict__ Q,
                                                    const unsigned short* __restrict__ K,
                                                    const unsigned short* __restrict__ Vt,
                                                    unsigned short* __restrict__ accP,
                                                    float* __restrict__ lP) {
  __shared__ unsigned short Ks[64 * 64];         // [key][dim], chunk-swizzled
  __shared__ unsigned short Vs[64 * 64];         // [dim][key], chunk-swizzled
  __shared__ unsigned short Ps[4 * 16 * LROW];   // per-wave P [q][key], padded
  int pair = blockIdx.x, h = blockIdx.y, bc = blockIdx.z;
  int b = bc / NSPLIT, c = bc % NSPLIT;
  int hb = b * 16 + h;
  int kh = h >> 2;
  int tid = threadIdx.x, wave = tid >> 6, lane = tid & 63, l15 = lane & 15, quad = lane >> 4;
  int l7 = l15 & 7;
  const unsigned short* Kg = K + (size_t)(b * 4 + kh) * 2048 * 64;
  const unsigned short* Vg = Vt + (size_t)(b * 4 + kh) * 64 * 2048;
  unsigned short* Pw = Ps + wave * 16 * LROW;
  int row0 = tid >> 3, col8 = (tid & 7) * 8;            // staging: rows {row0, row0+32}
  int dchunk = (((tid & 7) ^ (row0 & 7)) * 8);          // swizzled dest chunk (both rows)

#pragma unroll
  for (int half = 0; half < 2; half++) {
    int qt = (half == 0) ? pair : 31 - pair;
    int c0t = ((qt + 1) * c) / NSPLIT;
    int c1t = ((qt + 1) * (c + 1)) / NSPLIT;
    int q0 = qt * 64;
    const unsigned short* Qp = Q + (((size_t)hb * 2048) + q0 + wave * 16 + l15) * 64;
    bf16x8 qf0 = *(const bf16x8*)(Qp + quad * 8);
    bf16x8 qf1 = *(const bf16x8*)(Qp + 32 + quad * 8);
    f32x4 acc[4];
#pragma unroll
    for (int i = 0; i < 4; i++) acc[i] = (f32x4){0.f, 0.f, 0.f, 0.f};
    float l_lane = 0.f;

    if (c1t > c0t) {
      // prefetch first k-tile of chunk into regs
      int kf = c0t * 64;
      float4 pk0 = *(const float4*)(Kg + (size_t)(kf + row0) * 64 + col8);
      float4 pk1 = *(const float4*)(Kg + (size_t)(kf + row0 + 32) * 64 + col8);
      float4 pv0 = *(const float4*)(Vg + (size_t)row0 * 2048 + kf + col8);
      float4 pv1 = *(const float4*)(Vg + (size_t)(row0 + 32) * 2048 + kf + col8);

      for (int kt = c0t; kt < c1t; kt++) {
        int k0 = kt * 64;
        __syncthreads();  // prior consumers of Ks/Vs done
        *(float4*)(Ks + row0 * 64 + dchunk) = pk0;
        *(float4*)(Ks + (row0 + 32) * 64 + dchunk) = pk1;
        *(float4*)(Vs + row0 * 64 + dchunk) = pv0;
        *(float4*)(Vs + (row0 + 32) * 64 + dchunk) = pv1;
        if (kt + 1 < c1t) {  // prefetch next tile while computing this one
          int kn = k0 + 64;
          pk0 = *(const float4*)(Kg + (size_t)(kn + row0) * 64 + col8);
          pk1 = *(const float4*)(Kg + (size_t)(kn + row0 + 32) * 64 + col8);
          pv0 = *(const float4*)(Vg + (size_t)row0 * 2048 + kn + col8);
          pv1 = *(const float4*)(Vg + (size_t)(row0 + 32) * 2048 + kn + col8);
        }
        __syncthreads();

        // S^T: sv[mt][r] = S[q=l15][key=k0+mt*16+quad*4+r]
        f32x4 sv[4];
#pragma unroll
        for (int mt = 0; mt < 4; mt++) {
          sv[mt] = (f32x4){0.f, 0.f, 0.f, 0.f};
          bf16x8 k0f = *(const bf16x8*)(Ks + (mt * 16 + l15) * 64 + ((quad ^ l7) * 8));
          sv[mt] = __builtin_amdgcn_mfma_f32_16x16x32_bf16(k0f, qf0, sv[mt], 0, 0, 0);
          bf16x8 k1f = *(const bf16x8*)(Ks + (mt * 16 + l15) * 64 + (((4 + quad) ^ l7) * 8));
          sv[mt] = __builtin_amdgcn_mfma_f32_16x16x32_bf16(k1f, qf1, sv[mt], 0, 0, 0);
        }
        if (kt == qt) {  // diagonal: causal mask (key > q)
          int qg = q0 + wave * 16 + l15;
#pragma unroll
          for (int mt = 0; mt < 4; mt++) {
            int kg = k0 + mt * 16 + quad * 4;
#pragma unroll
            for (int r = 0; r < 4; r++)
              if (kg + r > qg) sv[mt][r] = -1e30f;
          }
        }
#pragma unroll
        for (int mt = 0; mt < 4; mt++) {
          float p0 = __builtin_amdgcn_exp2f(sv[mt][0]);
          float p1 = __builtin_amdgcn_exp2f(sv[mt][1]);
          float p2 = __builtin_amdgcn_exp2f(sv[mt][2]);
          float p3 = __builtin_amdgcn_exp2f(sv[mt][3]);
          l_lane += (p0 + p1) + (p2 + p3);
          unsigned int lo = __builtin_amdgcn_perm(__float_as_uint(p1), __float_as_uint(p0), 0x07060302u);
          unsigned int hi = __builtin_amdgcn_perm(__float_as_uint(p3), __float_as_uint(p2), 0x07060302u);
          *(uint2*)(Pw + l15 * LROW + mt * 16 + quad * 4) = make_uint2(lo, hi);
        }
        // PV: A = P rows (q=l15), B = V^T fragments. Same-wave DS ordering, no barrier.
#pragma unroll
        for (int step = 0; step < 2; step++) {
          bf16x8 pa = *(const bf16x8*)(Pw + l15 * LROW + step * 32 + quad * 8);
#pragma unroll
          for (int nt = 0; nt < 4; nt++) {
            bf16x8 vb = *(const bf16x8*)(Vs + (nt * 16 + l15) * 64 + (((step * 4 + quad) ^ l7) * 8));
            acc[nt] = __builtin_amdgcn_mfma_f32_16x16x32_bf16(pa, vb, acc[nt], 0, 0, 0);
          }
        }
      }
    }
    l_lane += __shfl_xor(l_lane, 16, 64);
    l_lane += __shfl_xor(l_lane, 32, 64);

    size_t slot = (size_t)(c * 32 + hb) * 2048 + q0 + wave * 16;
    if (lane < 16) lP[slot + l15] = l_lane;
    unsigned short* aP = accP + slot * 64;
#pragma unroll
    for (int r = 0; r < 4; r++)
#pragma unroll
      for (int nt = 0; nt < 4; nt++)
        aP[(size_t)(quad * 4 + r) * 64 + nt * 16 + l15] = f2bf(acc[nt][r]);
  }
}

// merge NSPLIT split-K partials: Y = (Σa_c)/(Σl_c), bf16 out. 4 d-elems/thread.
__global__ __launch_bounds__(256) void merge_kernel(const unsigned short* __restrict__ accP,
                                                    const float* __restrict__ lP,
                                                    unsigned short* __restrict__ Y) {
  int t = blockIdx.x * 256 + threadIdx.x;
  int d4 = (t & 15) * 4;
  int q  = (t >> 4) & 2047;
  int hb = t >> 15;
  const size_t CSTR = (size_t)32 * 2048 * 64;
  size_t pi = ((size_t)hb * 2048 + q) * 64 + d4;
  float y0 = 0.f, y1 = 0.f, y2 = 0.f, y3 = 0.f, l = 0.f;
#pragma unroll
  for (int c = 0; c < NSPLIT; c++) {
    ushort4 a = *(const ushort4*)(accP + pi + c * CSTR);
    y0 += bf2f(a.x); y1 += bf2f(a.y); y2 += bf2f(a.z); y3 += bf2f(a.w);
    l += lP[c * 65536 + hb * 2048 + q];
  }
  float inv = 1.f / l;
  ushort4 o;
  o.x = f2bf(y0 * inv); o.y = f2bf(y1 * inv); o.z = f2bf(y2 * inv); o.w = f2bf(y3 * inv);
  int b = hb >> 4, hh = hb & 15;
  *(ushort4*)(Y + ((size_t)(b * 2048 + q) * 1024) + hh * 64 + d4) = o;
}

// Proj GEMM out[4096][1024] = Y x Wproj^T. 128x64 TILE, grid (16,32) = 512 blocks
// (2/CU). Waves 2x2: wave = 64 rows x 32 cols, acc[4][2].
__global__ __launch_bounds__(256) void gemm_proj_kernel(const unsigned short* __restrict__ A,
                                                        const unsigned short* __restrict__ B,
                                                        float* __restrict__ C) {
  __shared__ unsigned short As[128 * 64];
  __shared__ unsigned short Bs[64 * 64];
  const int K = 1024, N = 1024;
  int tid = threadIdx.x;
  int wave = tid >> 6, lane = tid & 63, l15 = lane & 15, quad = lane >> 4;
  int wm = (wave >> 1) * 64, wn = (wave & 1) * 32;
  int n0 = blockIdx.x * 64, m0 = blockIdx.y * 128;
  f32x4 acc[4][2];
#pragma unroll
  for (int i = 0; i < 4; i++)
#pragma unroll
    for (int j = 0; j < 2; j++) acc[i][j] = (f32x4){0.f, 0.f, 0.f, 0.f};
  int srow = lane >> 3;
  int scol = ((lane & 7) ^ srow) * 8;
  for (int k0 = 0; k0 < K; k0 += 64) {
    __syncthreads();
#if HAVE_GLD
#pragma unroll
    for (int j = 0; j < 4; j++) {
      int row = wave * 32 + j * 8;
      gld16(A + (size_t)(m0 + row + srow) * K + k0 + scol, As + row * 64 + lane * 8);
    }
#pragma unroll
    for (int j = 0; j < 2; j++) {
      int row = wave * 16 + j * 8;
      gld16(B + (size_t)(n0 + row + srow) * K + k0 + scol, Bs + row * 64 + lane * 8);
    }
#else
#pragma unroll
    for (int j = 0; j < 4; j++) {
      int row = wave * 32 + j * 8;
      *(float4*)(As + row * 64 + lane * 8) = *(const float4*)(A + (size_t)(m0 + row + srow) * K + k0 + scol);
    }
#pragma unroll
    for (int j = 0; j < 2; j++) {
      int row = wave * 16 + j * 8;
      *(float4*)(Bs + row * 64 + lane * 8) = *(const float4*)(B + (size_t)(n0 + row + srow) * K + k0 + scol);
    }
#endif
    __syncthreads();
#pragma unroll
    for (int s = 0; s < 2; s++) {
      bf16x8 af[4], bf[2];
#pragma unroll
      for (int i = 0; i < 4; i++)
        af[i] = *(const bf16x8*)(As + (wm + i * 16 + l15) * 64 + (((s * 4 + quad) ^ (l15 & 7)) * 8));
#pragma unroll
      for (int j = 0; j < 2; j++)
        bf[j] = *(const bf16x8*)(Bs + (wn + j * 16 + l15) * 64 + (((s * 4 + quad) ^ (l15 & 7)) * 8));
#pragma unroll
      for (int i = 0; i < 4; i++)
#pragma unroll
        for (int j = 0; j < 2; j++)
          acc[i][j] = __builtin_amdgcn_mfma_f32_16x16x32_bf16(af[i], bf[j], acc[i][j], 0, 0, 0);
    }
  }
#pragma unroll
  for (int i = 0; i < 4; i++)
#pragma unroll
    for (int j = 0; j < 2; j++)
#pragma unroll
      for (int r = 0; r < 4; r++)
        C[(size_t)(m0 + wm + i * 16 + quad * 4 + r) * N + n0 + wn + j * 16 + l15] = acc[i][j][r];
}

extern "C" void kernel_launch(void* const* d_in, const int* in_sizes, int n_in,
                              void* d_out, int out_size, void* d_ws, size_t ws_size,
                              hipStream_t stream) {
  const float* x     = (const float*)d_in[0];
  const float* ve    = (const float*)d_in[1];
  const float* cosb  = (const float*)d_in[2];
  const float* sinb  = (const float*)d_in[3];
  // d_in[4] attn_mask: causal, hard-coded
  const float* Wq    = (const float*)d_in[5];
  const float* Wk    = (const float*)d_in[6];
  const float* Wv    = (const float*)d_in[7];
  const float* Wproj = (const float*)d_in[8];
  const float* Wgate = (const float*)d_in[9];
  float* out = (float*)d_out;
  char* ws = (char*)d_ws;

  size_t o = 0;
  unsigned short* xb   = (unsigned short*)(ws + o); o += (size_t)4096 * 1024 * 2;
  unsigned short* wqkv = (unsigned short*)(ws + o); o += (size_t)1536 * 1024 * 2;
  unsigned short* wpj  = (unsigned short*)(ws + o); o += (size_t)1024 * 1024 * 2;
  unsigned short* Qb   = (unsigned short*)(ws + o); o += (size_t)2 * 16 * 2048 * 64 * 2;
  unsigned short* Kb   = (unsigned short*)(ws + o); o += (size_t)2 * 4 * 2048 * 64 * 2;
  unsigned short* Vb   = (unsigned short*)(ws + o); o += (size_t)2 * 4 * 2048 * 64 * 2; // [b][kh][d][s]
  unsigned short* Yb   = (unsigned short*)(ws + o); o += (size_t)4096 * 1024 * 2;
  unsigned short* accP = (unsigned short*)(ws + o); o += (size_t)NSPLIT * 32 * 2048 * 64 * 2;
  float*          lP   = (float*)(ws + o);          o += (size_t)NSPLIT * 32 * 2048 * 4;

  hipLaunchKernelGGL(cvt_all_kernel, dim3(6656), dim3(256), 0, stream,
                     x, Wq, Wk, Wv, Wproj, xb, wqkv, wpj);
  hipLaunchKernelGGL(gemm_qkv_kernel, dim3(12, 64), dim3(256), 0, stream,
                     xb, wqkv, ve, cosb, sinb, Wgate, Qb, Kb, Vb);
  hipLaunchKernelGGL(flash_kernel, dim3(16, 16, 2 * NSPLIT), dim3(256), 0, stream,
                     Qb, Kb, Vb, accP, lP);
  hipLaunchKernelGGL(merge_kernel, dim3(4096), dim3(256), 0, stream, accP, lP, Yb);
  hipLaunchKernelGGL(gemm_proj_kernel, dim3(16, 32), dim3(256), 0, stream, Yb, wpj, out);
}